// Round 3
// baseline (1977.830 us; speedup 1.0000x reference)
//
#include <hip/hip_runtime.h>
#include <hip/hip_bf16.h>
#include <stdint.h>

// NOTE: resubmission of round-2 source — round-2 bench died at the container
// level (no compile/pytest/rocprof output); code audit found no hang/fault.

typedef __attribute__((ext_vector_type(8))) short short8;
typedef __attribute__((ext_vector_type(4))) float f32x4;

__device__ __forceinline__ float b2f(short s) {
    union { unsigned u; float f; } v; v.u = ((unsigned)(unsigned short)s) << 16; return v.f;
}
__device__ __forceinline__ short f2b(float f) {
    union { float f; unsigned u; } v; v.f = f;
    unsigned r = (v.u + 0x7FFF + ((v.u >> 16) & 1)) >> 16;
    return (short)r;
}

// async global->LDS, 16B per lane. LDS dest is wave-uniform base + lane*16.
__device__ __forceinline__ void gload16(const void* g, void* l) {
    __builtin_amdgcn_global_load_lds(
        (const __attribute__((address_space(1))) void*)(uintptr_t)g,
        (__attribute__((address_space(3))) void*)(uintptr_t)l,
        16, 0, 0);
}

#define BAR()    asm volatile("s_barrier" ::: "memory")
#define WAITV2() asm volatile("s_waitcnt vmcnt(2)" ::: "memory")
#define WAITV0() asm volatile("s_waitcnt vmcnt(0)" ::: "memory")
#define WAITL0() asm volatile("s_waitcnt lgkmcnt(0)" ::: "memory")
#define SGB()    __builtin_amdgcn_sched_barrier(0)

// ---------------- cast fp32 -> bf16 (8 elems/thread) ----------------
__global__ __launch_bounds__(256) void cast_bf16_kernel(
    const float* __restrict__ src, short* __restrict__ dst, int n8) {
    int i = blockIdx.x * 256 + threadIdx.x;
    if (i >= n8) return;
    const float4* s = (const float4*)src + (size_t)i * 2;
    float4 x0 = s[0], x1 = s[1];
    short8 o;
    o[0] = f2b(x0.x); o[1] = f2b(x0.y); o[2] = f2b(x0.z); o[3] = f2b(x0.w);
    o[4] = f2b(x1.x); o[5] = f2b(x1.y); o[6] = f2b(x1.z); o[7] = f2b(x1.w);
    *((short8*)dst + i) = o;
}

// ---------- transpose-cast W[K,N] f32 -> Wt[N,K] bf16 (8 k per thread) ----------
__global__ __launch_bounds__(256) void transpose_cast_kernel(
    const float* __restrict__ W, short* __restrict__ Wt, int K, int N, int total) {
    int t = blockIdx.x * 256 + threadIdx.x;
    if (t >= total) return;
    const float* src = W + (size_t)blockIdx.y * K * N;
    short* dst = Wt + (size_t)blockIdx.y * K * N;
    int n = t % N;
    int k0 = (t / N) * 8;
    short8 o;
#pragma unroll
    for (int i = 0; i < 8; i++) o[i] = f2b(src[(size_t)(k0 + i) * N + n]);
    *(short8*)(dst + (size_t)n * K + k0) = o;
}

// ---------------- generic C = relu(A @ Bt^T + bias), bf16 out ----------------
// (kept for selector layer1 only: N=128)
__global__ __launch_bounds__(256, 3)
void gemm_bt_bias_relu(const short* __restrict__ A, const short* __restrict__ Bt,
                       const float* __restrict__ bias, short* __restrict__ C,
                       int M, int N, int K) {
    __shared__ __align__(16) short As[128 * 32];
    __shared__ __align__(16) short Bs[128 * 32];
    const int tid = threadIdx.x;
    const int w = tid >> 6, lane = tid & 63;
    const int tm = blockIdx.y * 128, tn = blockIdx.x * 128;
    const int wm = (w & 1) * 64, wn = (w >> 1) * 64;
    const int r = lane & 15, q = lane >> 4, qk = q * 8;

    const int c0 = w * 2, c1 = w * 2 + 1;
    const int srow0 = c0 * 16 + (lane >> 2);
    const int srow1 = c1 * 16 + (lane >> 2);
    const int skk = (lane & 3) * 8;
    const short* gA0 = A + (size_t)(tm + srow0) * K + skk;
    const short* gA1 = A + (size_t)(tm + srow1) * K + skk;
    const short* gB0 = Bt + (size_t)(tn + srow0) * K + skk;
    const short* gB1 = Bt + (size_t)(tn + srow1) * K + skk;
    short* lA0 = &As[c0 * 512]; short* lA1 = &As[c1 * 512];
    short* lB0 = &Bs[c0 * 512]; short* lB1 = &Bs[c1 * 512];

    f32x4 acc[4][4] = {};
    for (int k0 = 0; k0 < K; k0 += 32) {
        gload16(gA0 + k0, lA0);
        gload16(gA1 + k0, lA1);
        gload16(gB0 + k0, lB0);
        gload16(gB1 + k0, lB1);
        __syncthreads();
        short8 a[4], b[4];
#pragma unroll
        for (int i = 0; i < 4; i++) a[i] = *(const short8*)&As[(wm + i * 16 + r) * 32 + qk];
#pragma unroll
        for (int j = 0; j < 4; j++) b[j] = *(const short8*)&Bs[(wn + j * 16 + r) * 32 + qk];
#pragma unroll
        for (int i = 0; i < 4; i++)
#pragma unroll
            for (int j = 0; j < 4; j++)
                acc[i][j] = __builtin_amdgcn_mfma_f32_16x16x32_bf16(a[i], b[j], acc[i][j], 0, 0, 0);
        __syncthreads();
    }
#pragma unroll
    for (int j = 0; j < 4; j++) {
        int col = tn + wn + j * 16 + r;
        float bj = bias[col];
#pragma unroll
        for (int i = 0; i < 4; i++)
#pragma unroll
            for (int rr = 0; rr < 4; rr++) {
                int row = tm + wm + i * 16 + q * 4 + rr;
                float v = fmaxf(acc[i][j][rr] + bj, 0.f);
                C[(size_t)row * N + col] = f2b(v);
            }
    }
}

// ---------------- selector last layer + softmax ----------------
__global__ __launch_bounds__(256)
void selector_softmax(const short* __restrict__ s1, const short* __restrict__ Ws2t,
                      const float* __restrict__ bs2, float* __restrict__ wsel) {
    int tid = threadIdx.x;
    int row = blockIdx.x * 16 + (tid >> 4);
    int e = tid & 15;
    const short8* a = (const short8*)(s1 + (size_t)row * 128);
    const short8* b = (const short8*)(Ws2t + (size_t)e * 128);
    float acc = bs2[e];
#pragma unroll
    for (int kk = 0; kk < 16; ++kk) {
        short8 av = a[kk], bv = b[kk];
#pragma unroll
        for (int i = 0; i < 8; i++) acc = fmaf(b2f(av[i]), b2f(bv[i]), acc);
    }
    float m = acc;
#pragma unroll
    for (int off = 8; off >= 1; off >>= 1) m = fmaxf(m, __shfl_xor(m, off, 16));
    float ex = __expf(acc - m);
    float s = ex;
#pragma unroll
    for (int off = 8; off >= 1; off >>= 1) s += __shfl_xor(s, off, 16);
    wsel[(size_t)row * 16 + e] = ex / s;
}

// ---------------- out init: out[b,a] = sum_e wsel[b,e]*be2[e,a] ----------------
__global__ __launch_bounds__(256)
void out_init_kernel(const float* __restrict__ wsel, const float* __restrict__ be2,
                     float* __restrict__ out) {
    int i = blockIdx.x * 256 + threadIdx.x;      // over B*32
    int row = i >> 5, a = i & 31;
    const float* wr = wsel + (size_t)row * 16;
    float acc = 0.f;
#pragma unroll
    for (int e = 0; e < 16; e++) acc = fmaf(wr[e], be2[e * 32 + a], acc);
    out[i] = acc;
}

// ================= 256x256 GEMM, 2-barrier/tile drift-overlap schedule =================
// C = bf16(relu(A @ Bt^T + bias)). 8 waves (2Mx4N), BK=64, LDS 128KiB double-buffered.
// Swizzle: byte ^= (row&7)<<4, via pre-swizzled global source + swizzled ds_read.
// No intra-tile barriers: the 2 waves/SIMD drift so ds_reads overlap MFMA cross-wave.
__global__ __launch_bounds__(512, 2)
void gemm256(const short* __restrict__ A, const short* __restrict__ Bt,
             const float* __restrict__ bias, short* __restrict__ C,
             int M, int N, int K) {
    extern __shared__ __align__(16) short lds[];
    const int tid = threadIdx.x;
    const int w = tid >> 6, lane = tid & 63;
    const int wr = w >> 2, wc = w & 3;

    // bijective XCD swizzle (nwg % 8 == 0 for all our launches)
    const int gx = gridDim.x;
    const int b = blockIdx.y * gx + blockIdx.x;
    const int per = (gx * gridDim.y) >> 3;
    const int sb = (b & 7) * per + (b >> 3);
    const int bx = sb % gx, by = sb / gx;
    const int tm = by * 256, tn = bx * 256;

    const int rih = w * 8 + (lane >> 3);
    const int colel = (((lane & 7) ^ (lane >> 3)) << 3);
    const short* pA = A + (size_t)(tm + rih) * K + colel;
    const short* pB = Bt + (size_t)(tn + rih) * K + colel;
    const size_t rK64 = (size_t)64 * K, rK128 = (size_t)128 * K;
    short* const ldsw = lds + w * 512;

#define STG_A(buf, h, t) do { \
        const short* s_ = pA + (size_t)(h) * rK128 + (size_t)(t) * 64; \
        short* d_ = ldsw + (buf) * 32768 + (h) * 8192; \
        gload16(s_, d_); \
        gload16(s_ + rK64, d_ + 4096); } while (0)
#define STG_B(buf, h, t) do { \
        const short* s_ = pB + (size_t)(h) * rK128 + (size_t)(t) * 64; \
        short* d_ = ldsw + (buf) * 32768 + 16384 + (h) * 8192; \
        gload16(s_, d_); \
        gload16(s_ + rK64, d_ + 4096); } while (0)

    const int rA = lane & 15, q = lane >> 4;
    const int csw0 = ((q << 4)) ^ ((lane & 7) << 4);
    const int csw1 = (64 + (q << 4)) ^ ((lane & 7) << 4);
    const char* const ldsB_ = (const char*)lds;
    const int aBase0 = wr * 16384 + rA * 128;
    const int bBase0 = 32768 + (wc >> 1) * 16384 + ((wc & 1) * 64 + rA) * 128;

    f32x4 acc[8][4] = {};
    short8 a[4][2], b0[2][2], b1[2][2];
    const int nt = K >> 6;

    // prologue: tile0 fully + tile1.A0 (10 loads); allow last 2 in flight
    STG_A(0, 0, 0); STG_A(0, 1, 0); STG_B(0, 0, 0); STG_B(0, 1, 0);
    STG_A(1, 0, 1);
    WAITV2(); BAR();

    for (int t = 0; t < nt; ++t) {
        const int cur = t & 1, nxt = cur ^ 1;
        const char* pa = ldsB_ + cur * 65536 + aBase0;
        const char* pb = ldsB_ + cur * 65536 + bBase0;
        // ph1: a-lo + b0 ; stage A1(t+1) ; quad (lo,lo)
#pragma unroll
        for (int m = 0; m < 4; m++) {
            a[m][0] = *(const short8*)(pa + m * 2048 + csw0);
            a[m][1] = *(const short8*)(pa + m * 2048 + csw1);
        }
#pragma unroll
        for (int n = 0; n < 2; n++) {
            b0[n][0] = *(const short8*)(pb + n * 2048 + csw0);
            b0[n][1] = *(const short8*)(pb + n * 2048 + csw1);
        }
        if (t + 1 < nt) STG_A(nxt, 1, t + 1);
        WAITL0(); SGB();
        __builtin_amdgcn_s_setprio(1);
#pragma unroll
        for (int m = 0; m < 4; m++)
#pragma unroll
            for (int n = 0; n < 2; n++) {
                acc[m][n] = __builtin_amdgcn_mfma_f32_16x16x32_bf16(a[m][0], b0[n][0], acc[m][n], 0, 0, 0);
                acc[m][n] = __builtin_amdgcn_mfma_f32_16x16x32_bf16(a[m][1], b0[n][1], acc[m][n], 0, 0, 0);
            }
        __builtin_amdgcn_s_setprio(0);
        // ph2: b1 ; stage B0(t+1) ; quad (lo,hi)
#pragma unroll
        for (int n = 0; n < 2; n++) {
            b1[n][0] = *(const short8*)(pb + (2 + n) * 2048 + csw0);
            b1[n][1] = *(const short8*)(pb + (2 + n) * 2048 + csw1);
        }
        if (t + 1 < nt) STG_B(nxt, 0, t + 1);
        WAITL0(); SGB();
        __builtin_amdgcn_s_setprio(1);
#pragma unroll
        for (int m = 0; m < 4; m++)
#pragma unroll
            for (int n = 0; n < 2; n++) {
                acc[m][2 + n] = __builtin_amdgcn_mfma_f32_16x16x32_bf16(a[m][0], b1[n][0], acc[m][2 + n], 0, 0, 0);
                acc[m][2 + n] = __builtin_amdgcn_mfma_f32_16x16x32_bf16(a[m][1], b1[n][1], acc[m][2 + n], 0, 0, 0);
            }
        __builtin_amdgcn_s_setprio(0);
        // ph3: a-hi ; stage B1(t+1) ; quad (hi,hi)
#pragma unroll
        for (int m = 0; m < 4; m++) {
            a[m][0] = *(const short8*)(pa + (4 + m) * 2048 + csw0);
            a[m][1] = *(const short8*)(pa + (4 + m) * 2048 + csw1);
        }
        if (t + 1 < nt) STG_B(nxt, 1, t + 1);
        WAITL0(); SGB();
        __builtin_amdgcn_s_setprio(1);
#pragma unroll
        for (int m = 0; m < 4; m++)
#pragma unroll
            for (int n = 0; n < 2; n++) {
                acc[4 + m][2 + n] = __builtin_amdgcn_mfma_f32_16x16x32_bf16(a[m][0], b1[n][0], acc[4 + m][2 + n], 0, 0, 0);
                acc[4 + m][2 + n] = __builtin_amdgcn_mfma_f32_16x16x32_bf16(a[m][1], b1[n][1], acc[4 + m][2 + n], 0, 0, 0);
            }
        __builtin_amdgcn_s_setprio(0);
        // ph4: quad (hi,lo) ; buffer transition
        __builtin_amdgcn_s_setprio(1);
#pragma unroll
        for (int m = 0; m < 4; m++)
#pragma unroll
            for (int n = 0; n < 2; n++) {
                acc[4 + m][n] = __builtin_amdgcn_mfma_f32_16x16x32_bf16(a[m][0], b0[n][0], acc[4 + m][n], 0, 0, 0);
                acc[4 + m][n] = __builtin_amdgcn_mfma_f32_16x16x32_bf16(a[m][1], b0[n][1], acc[4 + m][n], 0, 0, 0);
            }
        __builtin_amdgcn_s_setprio(0);
        BAR();                                   // all waves done reading cur
        if (t + 2 < nt) { STG_A(cur, 0, t + 2); WAITV2(); }
        else WAITV0();
        BAR();                                   // nxt complete
    }
#undef STG_A
#undef STG_B

    // epilogue
    float biasv[4];
#pragma unroll
    for (int n = 0; n < 4; n++) biasv[n] = bias[tn + wc * 64 + n * 16 + rA];
    const int q4 = q * 4;
#pragma unroll
    for (int m = 0; m < 8; m++)
#pragma unroll
        for (int rr = 0; rr < 4; rr++) {
            const int row = tm + wr * 128 + m * 16 + q4 + rr;
#pragma unroll
            for (int n = 0; n < 4; n++) {
                const int col = tn + wc * 64 + n * 16 + rA;
                float v = fmaxf(acc[m][n][rr] + biasv[n], 0.f);
                C[(size_t)row * N + col] = f2b(v);
            }
        }
}

// ================= fused MoE: for e in 16 { GEMM1(256x256xK512) -> eh -> GEMM2(K256,N32) } ==============
// A = hbuf tile (same for all experts). eh via 64KB LDS halves in buf1 (free after main loop).
// out accumulated by global RMW per expert (out pre-inited with sum_e wsel*be2 by out_init_kernel).
__global__ __launch_bounds__(512, 2)
void moe_kernel(const short* __restrict__ hbuf, const short* __restrict__ We1t,
                const short* __restrict__ We2t, const float* __restrict__ be1,
                const float* __restrict__ wsel, float* __restrict__ out) {
    extern __shared__ __align__(16) short lds[];
    const int tid = threadIdx.x;
    const int w = tid >> 6, lane = tid & 63;
    const int wr = w >> 2, wc = w & 3;
    const int b = blockIdx.x;
    const int sb = (b & 7) * 32 + (b >> 3);      // 256 blocks, bijective XCD swizzle
    const int tm = sb * 256;

    const int rih = w * 8 + (lane >> 3);
    const int colel = (((lane & 7) ^ (lane >> 3)) << 3);
    const short* pA = hbuf + (size_t)(tm + rih) * 512 + colel;
    const short* pB0 = We1t + (size_t)rih * 512 + colel;
    short* const ldsw = lds + w * 512;

#define MSTG_A(buf, h, t) do { \
        const short* s_ = pA + (size_t)(h) * 65536 + (size_t)(t) * 64; \
        short* d_ = ldsw + (buf) * 32768 + (h) * 8192; \
        gload16(s_, d_); \
        gload16(s_ + 32768, d_ + 4096); } while (0)
#define MSTG_B(P, buf, h, t) do { \
        const short* s_ = (P) + (size_t)(h) * 65536 + (size_t)(t) * 64; \
        short* d_ = ldsw + (buf) * 32768 + 16384 + (h) * 8192; \
        gload16(s_, d_); \
        gload16(s_ + 32768, d_ + 4096); } while (0)

    const int rA = lane & 15, q = lane >> 4;
    const int csw0 = ((q << 4)) ^ ((lane & 7) << 4);
    const int csw1 = (64 + (q << 4)) ^ ((lane & 7) << 4);
    const char* const ldsB_ = (const char*)lds;
    const int aBase0 = wr * 16384 + rA * 128;
    const int bBase0 = 32768 + (wc >> 1) * 16384 + ((wc & 1) * 64 + rA) * 128;
    const int q4 = q * 4;

    short8 a[4][2], b0[2][2], b1[2][2];

    // prologue: expert 0 tile 0 (8 loads)
    {
        const short* pBe = pB0;
        MSTG_A(0, 0, 0); MSTG_A(0, 1, 0);
        MSTG_B(pBe, 0, 0, 0); MSTG_B(pBe, 0, 1, 0);
    }

#pragma unroll 1
    for (int e = 0; e < 16; ++e) {
        const short* pBe = pB0 + (size_t)e * 131072;
        WAITV0(); BAR();                          // tile0 staged; also drains epilogue vmem
        f32x4 acc[8][4] = {};
#pragma unroll 1
        for (int t = 0; t < 8; ++t) {
            const int cur = t & 1, nxt = cur ^ 1;
            const char* pa = ldsB_ + cur * 65536 + aBase0;
            const char* pb = ldsB_ + cur * 65536 + bBase0;
#pragma unroll
            for (int m = 0; m < 4; m++) {
                a[m][0] = *(const short8*)(pa + m * 2048 + csw0);
                a[m][1] = *(const short8*)(pa + m * 2048 + csw1);
            }
#pragma unroll
            for (int n = 0; n < 2; n++) {
                b0[n][0] = *(const short8*)(pb + n * 2048 + csw0);
                b0[n][1] = *(const short8*)(pb + n * 2048 + csw1);
            }
            if (t < 7) MSTG_A(nxt, 1, t + 1);
            if (t == 0) MSTG_A(nxt, 0, 1);
            WAITL0(); SGB();
            __builtin_amdgcn_s_setprio(1);
#pragma unroll
            for (int m = 0; m < 4; m++)
#pragma unroll
                for (int n = 0; n < 2; n++) {
                    acc[m][n] = __builtin_amdgcn_mfma_f32_16x16x32_bf16(a[m][0], b0[n][0], acc[m][n], 0, 0, 0);
                    acc[m][n] = __builtin_amdgcn_mfma_f32_16x16x32_bf16(a[m][1], b0[n][1], acc[m][n], 0, 0, 0);
                }
            __builtin_amdgcn_s_setprio(0);
#pragma unroll
            for (int n = 0; n < 2; n++) {
                b1[n][0] = *(const short8*)(pb + (2 + n) * 2048 + csw0);
                b1[n][1] = *(const short8*)(pb + (2 + n) * 2048 + csw1);
            }
            if (t < 7) MSTG_B(pBe, nxt, 0, t + 1);
            WAITL0(); SGB();
            __builtin_amdgcn_s_setprio(1);
#pragma unroll
            for (int m = 0; m < 4; m++)
#pragma unroll
                for (int n = 0; n < 2; n++) {
                    acc[m][2 + n] = __builtin_amdgcn_mfma_f32_16x16x32_bf16(a[m][0], b1[n][0], acc[m][2 + n], 0, 0, 0);
                    acc[m][2 + n] = __builtin_amdgcn_mfma_f32_16x16x32_bf16(a[m][1], b1[n][1], acc[m][2 + n], 0, 0, 0);
                }
            __builtin_amdgcn_s_setprio(0);
#pragma unroll
            for (int m = 0; m < 4; m++) {
                a[m][0] = *(const short8*)(pa + (4 + m) * 2048 + csw0);
                a[m][1] = *(const short8*)(pa + (4 + m) * 2048 + csw1);
            }
            if (t < 7) MSTG_B(pBe, nxt, 1, t + 1);
            WAITL0(); SGB();
            __builtin_amdgcn_s_setprio(1);
#pragma unroll
            for (int m = 0; m < 4; m++)
#pragma unroll
                for (int n = 0; n < 2; n++) {
                    acc[4 + m][2 + n] = __builtin_amdgcn_mfma_f32_16x16x32_bf16(a[m][0], b1[n][0], acc[4 + m][2 + n], 0, 0, 0);
                    acc[4 + m][2 + n] = __builtin_amdgcn_mfma_f32_16x16x32_bf16(a[m][1], b1[n][1], acc[4 + m][2 + n], 0, 0, 0);
                }
            __builtin_amdgcn_s_setprio(0);
            __builtin_amdgcn_s_setprio(1);
#pragma unroll
            for (int m = 0; m < 4; m++)
#pragma unroll
                for (int n = 0; n < 2; n++) {
                    acc[4 + m][n] = __builtin_amdgcn_mfma_f32_16x16x32_bf16(a[m][0], b0[n][0], acc[4 + m][n], 0, 0, 0);
                    acc[4 + m][n] = __builtin_amdgcn_mfma_f32_16x16x32_bf16(a[m][1], b0[n][1], acc[4 + m][n], 0, 0, 0);
                }
            __builtin_amdgcn_s_setprio(0);
            BAR();
            if (t < 6) { MSTG_A(cur, 0, t + 2); WAITV2(); }
            else WAITV0();
            BAR();
        }

        // --- epilogue: stage next expert's tile0 early, then GEMM2 via eh halves in buf1 ---
        if (e + 1 < 16) {
            const short* pBn = pB0 + (size_t)(e + 1) * 131072;
            MSTG_A(0, 0, 0); MSTG_A(0, 1, 0);
            MSTG_B(pBn, 0, 0, 0); MSTG_B(pBn, 0, 1, 0);
        }
        f32x4 g2[2][2] = {};
#pragma unroll
        for (int hh = 0; hh < 2; ++hh) {
            if ((wc >> 1) == hh) {
                const int chb = (wc & 1) * 64;
#pragma unroll
                for (int n = 0; n < 4; n++) {
                    const int col = chb + n * 16 + rA;                 // within-half col
                    const float bv = be1[e * 256 + hh * 128 + col];
#pragma unroll
                    for (int m = 0; m < 8; m++)
#pragma unroll
                        for (int rr = 0; rr < 4; rr++) {
                            const int row = wr * 128 + m * 16 + q4 + rr;
                            const int byt = 65536 + row * 256 + ((col * 2) ^ ((row & 7) << 4));
                            *(short*)((char*)lds + byt) = f2b(fmaxf(acc[m][n][rr] + bv, 0.f));
                        }
                }
            }
            WAITL0(); BAR();                      // eh half ready
#pragma unroll
            for (int k2 = 0; k2 < 4; ++k2) {
                short8 a2[2], b2[2];
#pragma unroll
                for (int m2 = 0; m2 < 2; m2++) {
                    const int row = w * 32 + m2 * 16 + rA;
                    a2[m2] = *(const short8*)((const char*)lds + 65536 + row * 256 +
                                              ((k2 * 64 + q * 16) ^ ((row & 7) << 4)));
                }
#pragma unroll
                for (int n2 = 0; n2 < 2; n2++)
                    b2[n2] = *(const short8*)(We2t + (size_t)(e * 32 + n2 * 16 + rA) * 256 +
                                              hh * 128 + k2 * 32 + q * 8);
#pragma unroll
                for (int m2 = 0; m2 < 2; m2++)
#pragma unroll
                    for (int n2 = 0; n2 < 2; n2++)
                        g2[m2][n2] = __builtin_amdgcn_mfma_f32_16x16x32_bf16(a2[m2], b2[n2], g2[m2][n2], 0, 0, 0);
            }
            WAITL0(); BAR();                      // reads done before next half overwrites
        }
        // out += wsel[:,e] * g2  (rows owned exclusively by this block)
#pragma unroll
        for (int m2 = 0; m2 < 2; m2++)
#pragma unroll
            for (int rr = 0; rr < 4; rr++) {
                const int row = tm + w * 32 + m2 * 16 + q4 + rr;
                const float ws = wsel[(size_t)row * 16 + e];
#pragma unroll
                for (int n2 = 0; n2 < 2; n2++) {
                    float* po = out + (size_t)row * 32 + n2 * 16 + rA;
                    *po = *po + ws * g2[m2][n2][rr];
                }
            }
    }
#undef MSTG_A
#undef MSTG_B
}

extern "C" void kernel_launch(void* const* d_in, const int* in_sizes, int n_in,
                              void* d_out, int out_size, void* d_ws, size_t ws_size,
                              hipStream_t stream) {
    const float* obs = (const float*)d_in[0];
    const float* Wb0 = (const float*)d_in[1]; const float* bb0 = (const float*)d_in[2];
    const float* Wb1 = (const float*)d_in[3]; const float* bb1 = (const float*)d_in[4];
    const float* Wb2 = (const float*)d_in[5]; const float* bb2 = (const float*)d_in[6];
    const float* We1 = (const float*)d_in[7]; const float* be1 = (const float*)d_in[8];
    const float* We2 = (const float*)d_in[9]; const float* be2 = (const float*)d_in[10];
    const float* Ws0 = (const float*)d_in[11]; const float* bs0 = (const float*)d_in[12];
    const float* Ws1 = (const float*)d_in[13]; const float* bs1 = (const float*)d_in[14];
    const float* Ws2 = (const float*)d_in[15]; const float* bs2 = (const float*)d_in[16];

    const int B = 65536;
    char* ws = (char*)d_ws;
    size_t off = 0;
    auto alloc = [&](size_t bytes) { void* p = ws + off; off += (bytes + 255) & ~(size_t)255; return p; };
    short* obs_bf = (short*)alloc((size_t)B * 512 * 2);
    short* h1     = (short*)alloc((size_t)B * 1024 * 2);
    short* h2     = (short*)alloc((size_t)B * 1024 * 2);
    short* hbuf   = (short*)alloc((size_t)B * 512 * 2);
    short* s0     = (short*)alloc((size_t)B * 256 * 2);
    short* s1     = (short*)alloc((size_t)B * 128 * 2);
    float* wsel   = (float*)alloc((size_t)B * 16 * 4);
    short* Wb0t   = (short*)alloc((size_t)512 * 1024 * 2);
    short* Wb1t   = (short*)alloc((size_t)1024 * 1024 * 2);
    short* Wb2t   = (short*)alloc((size_t)1024 * 512 * 2);
    short* We1t   = (short*)alloc((size_t)16 * 512 * 256 * 2);
    short* We2t   = (short*)alloc((size_t)16 * 256 * 32 * 2);
    short* Ws0t   = (short*)alloc((size_t)512 * 256 * 2);
    short* Ws1t   = (short*)alloc((size_t)256 * 128 * 2);
    short* Ws2t   = (short*)alloc((size_t)128 * 16 * 2);

    static int inited = 0;
    if (!inited) {
        hipFuncSetAttribute(reinterpret_cast<const void*>(gemm256),
                            hipFuncAttributeMaxDynamicSharedMemorySize, 131072);
        hipFuncSetAttribute(reinterpret_cast<const void*>(moe_kernel),
                            hipFuncAttributeMaxDynamicSharedMemorySize, 131072);
        inited = 1;
    }

    // --- preprocessing: casts / transposes ---
    cast_bf16_kernel<<<(B * 512 / 8 + 255) / 256, 256, 0, stream>>>(obs, obs_bf, B * 512 / 8);
    transpose_cast_kernel<<<dim3((1024 * 512 / 8 + 255) / 256, 1), 256, 0, stream>>>(Wb0, Wb0t, 512, 1024, 1024 * 512 / 8);
    transpose_cast_kernel<<<dim3((1024 * 1024 / 8 + 255) / 256, 1), 256, 0, stream>>>(Wb1, Wb1t, 1024, 1024, 1024 * 1024 / 8);
    transpose_cast_kernel<<<dim3((512 * 1024 / 8 + 255) / 256, 1), 256, 0, stream>>>(Wb2, Wb2t, 1024, 512, 512 * 1024 / 8);
    transpose_cast_kernel<<<dim3((256 * 512 / 8 + 255) / 256, 16), 256, 0, stream>>>(We1, We1t, 512, 256, 256 * 512 / 8);
    transpose_cast_kernel<<<dim3((32 * 256 / 8 + 255) / 256, 16), 256, 0, stream>>>(We2, We2t, 256, 32, 32 * 256 / 8);
    transpose_cast_kernel<<<dim3((256 * 512 / 8 + 255) / 256, 1), 256, 0, stream>>>(Ws0, Ws0t, 512, 256, 256 * 512 / 8);
    transpose_cast_kernel<<<dim3((128 * 256 / 8 + 255) / 256, 1), 256, 0, stream>>>(Ws1, Ws1t, 256, 128, 128 * 256 / 8);
    transpose_cast_kernel<<<dim3((16 * 128 / 8 + 255) / 256, 1), 256, 0, stream>>>(Ws2, Ws2t, 128, 16, 16 * 128 / 8);

    // --- selector chain ---
    gemm256<<<dim3(1, B / 256), 512, 131072, stream>>>(obs_bf, Ws0t, bs0, s0, B, 256, 512);
    gemm_bt_bias_relu<<<dim3(1, B / 128), 256, 0, stream>>>(s0, Ws1t, bs1, s1, B, 128, 256);
    selector_softmax<<<B / 16, 256, 0, stream>>>(s1, Ws2t, bs2, wsel);
    out_init_kernel<<<B * 32 / 256, 256, 0, stream>>>(wsel, be2, (float*)d_out);

    // --- backbone ---
    gemm256<<<dim3(4, B / 256), 512, 131072, stream>>>(obs_bf, Wb0t, bb0, h1, B, 1024, 512);
    gemm256<<<dim3(4, B / 256), 512, 131072, stream>>>(h1, Wb1t, bb1, h2, B, 1024, 1024);
    gemm256<<<dim3(2, B / 256), 512, 131072, stream>>>(h2, Wb2t, bb2, hbuf, B, 512, 1024);

    // --- fused experts (GEMM1 + GEMM2 + weighted fusion in one kernel) ---
    moe_kernel<<<256, 512, 131072, stream>>>(hbuf, We1t, We2t, be1, wsel, (float*)d_out);
}

// Round 4
// 1116.858 us; speedup vs baseline: 1.7709x; 1.7709x over previous
//
#include <hip/hip_runtime.h>
#include <hip/hip_bf16.h>
#include <stdint.h>

typedef __attribute__((ext_vector_type(8))) short short8;
typedef __attribute__((ext_vector_type(4))) float f32x4;

__device__ __forceinline__ float b2f(short s) {
    union { unsigned u; float f; } v; v.u = ((unsigned)(unsigned short)s) << 16; return v.f;
}
__device__ __forceinline__ short f2b(float f) {
    union { float f; unsigned u; } v; v.f = f;
    unsigned r = (v.u + 0x7FFF + ((v.u >> 16) & 1)) >> 16;
    return (short)r;
}

// async global->LDS, 16B per lane. LDS dest is wave-uniform base + lane*16.
__device__ __forceinline__ void gload16(const void* g, void* l) {
    __builtin_amdgcn_global_load_lds(
        (const __attribute__((address_space(1))) void*)(uintptr_t)g,
        (__attribute__((address_space(3))) void*)(uintptr_t)l,
        16, 0, 0);
}

#define BAR()    asm volatile("s_barrier" ::: "memory")
#define WAITV0() asm volatile("s_waitcnt vmcnt(0)" ::: "memory")
#define WAITL0() asm volatile("s_waitcnt lgkmcnt(0)" ::: "memory")
#define SGB()    __builtin_amdgcn_sched_barrier(0)

// ---------------- cast fp32 -> bf16 (8 elems/thread) ----------------
__global__ __launch_bounds__(256) void cast_bf16_kernel(
    const float* __restrict__ src, short* __restrict__ dst, int n8) {
    int i = blockIdx.x * 256 + threadIdx.x;
    if (i >= n8) return;
    const float4* s = (const float4*)src + (size_t)i * 2;
    float4 x0 = s[0], x1 = s[1];
    short8 o;
    o[0] = f2b(x0.x); o[1] = f2b(x0.y); o[2] = f2b(x0.z); o[3] = f2b(x0.w);
    o[4] = f2b(x1.x); o[5] = f2b(x1.y); o[6] = f2b(x1.z); o[7] = f2b(x1.w);
    *((short8*)dst + i) = o;
}

// ---------- transpose-cast W[K,N] f32 -> Wt[N,K] bf16 (8 k per thread) ----------
__global__ __launch_bounds__(256) void transpose_cast_kernel(
    const float* __restrict__ W, short* __restrict__ Wt, int K, int N, int total) {
    int t = blockIdx.x * 256 + threadIdx.x;
    if (t >= total) return;
    const float* src = W + (size_t)blockIdx.y * K * N;
    short* dst = Wt + (size_t)blockIdx.y * K * N;
    int n = t % N;
    int k0 = (t / N) * 8;
    short8 o;
#pragma unroll
    for (int i = 0; i < 8; i++) o[i] = f2b(src[(size_t)(k0 + i) * N + n]);
    *(short8*)(dst + (size_t)n * K + k0) = o;
}

// ---------- repack We2[16][256][32] f32 -> Bt2[32][4096] bf16 (Bt2[a][e*256+h]) ----------
__global__ __launch_bounds__(256) void repack_We2_kernel(
    const float* __restrict__ We2, short* __restrict__ Bt2) {
    int t = blockIdx.x * 256 + threadIdx.x;      // 16384 threads: (e, a, h0/8)
    int h0 = (t & 31) * 8;
    int a = (t >> 5) & 31;
    int e = t >> 10;
    short8 o;
#pragma unroll
    for (int j = 0; j < 8; j++) o[j] = f2b(We2[((size_t)e * 256 + h0 + j) * 32 + a]);
    *(short8*)(Bt2 + (size_t)a * 4096 + e * 256 + h0) = o;
}

// ---------------- generic C = relu(A @ Bt^T + bias), bf16 out ----------------
// (kept for selector layer1 only: N=128)
__global__ __launch_bounds__(256, 3)
void gemm_bt_bias_relu(const short* __restrict__ A, const short* __restrict__ Bt,
                       const float* __restrict__ bias, short* __restrict__ C,
                       int M, int N, int K) {
    __shared__ __align__(16) short As[128 * 32];
    __shared__ __align__(16) short Bs[128 * 32];
    const int tid = threadIdx.x;
    const int w = tid >> 6, lane = tid & 63;
    const int tm = blockIdx.y * 128, tn = blockIdx.x * 128;
    const int wm = (w & 1) * 64, wn = (w >> 1) * 64;
    const int r = lane & 15, q = lane >> 4, qk = q * 8;

    const int c0 = w * 2, c1 = w * 2 + 1;
    const int srow0 = c0 * 16 + (lane >> 2);
    const int srow1 = c1 * 16 + (lane >> 2);
    const int skk = (lane & 3) * 8;
    const short* gA0 = A + (size_t)(tm + srow0) * K + skk;
    const short* gA1 = A + (size_t)(tm + srow1) * K + skk;
    const short* gB0 = Bt + (size_t)(tn + srow0) * K + skk;
    const short* gB1 = Bt + (size_t)(tn + srow1) * K + skk;
    short* lA0 = &As[c0 * 512]; short* lA1 = &As[c1 * 512];
    short* lB0 = &Bs[c0 * 512]; short* lB1 = &Bs[c1 * 512];

    f32x4 acc[4][4] = {};
    for (int k0 = 0; k0 < K; k0 += 32) {
        gload16(gA0 + k0, lA0);
        gload16(gA1 + k0, lA1);
        gload16(gB0 + k0, lB0);
        gload16(gB1 + k0, lB1);
        __syncthreads();
        short8 a[4], b[4];
#pragma unroll
        for (int i = 0; i < 4; i++) a[i] = *(const short8*)&As[(wm + i * 16 + r) * 32 + qk];
#pragma unroll
        for (int j = 0; j < 4; j++) b[j] = *(const short8*)&Bs[(wn + j * 16 + r) * 32 + qk];
#pragma unroll
        for (int i = 0; i < 4; i++)
#pragma unroll
            for (int j = 0; j < 4; j++)
                acc[i][j] = __builtin_amdgcn_mfma_f32_16x16x32_bf16(a[i], b[j], acc[i][j], 0, 0, 0);
        __syncthreads();
    }
#pragma unroll
    for (int j = 0; j < 4; j++) {
        int col = tn + wn + j * 16 + r;
        float bj = bias[col];
#pragma unroll
        for (int i = 0; i < 4; i++)
#pragma unroll
            for (int rr = 0; rr < 4; rr++) {
                int row = tm + wm + i * 16 + q * 4 + rr;
                float v = fmaxf(acc[i][j][rr] + bj, 0.f);
                C[(size_t)row * N + col] = f2b(v);
            }
    }
}

// ---------------- selector last layer + softmax ----------------
__global__ __launch_bounds__(256)
void selector_softmax(const short* __restrict__ s1, const short* __restrict__ Ws2t,
                      const float* __restrict__ bs2, float* __restrict__ wsel) {
    int tid = threadIdx.x;
    int row = blockIdx.x * 16 + (tid >> 4);
    int e = tid & 15;
    const short8* a = (const short8*)(s1 + (size_t)row * 128);
    const short8* b = (const short8*)(Ws2t + (size_t)e * 128);
    float acc = bs2[e];
#pragma unroll
    for (int kk = 0; kk < 16; ++kk) {
        short8 av = a[kk], bv = b[kk];
#pragma unroll
        for (int i = 0; i < 8; i++) acc = fmaf(b2f(av[i]), b2f(bv[i]), acc);
    }
    float m = acc;
#pragma unroll
    for (int off = 8; off >= 1; off >>= 1) m = fmaxf(m, __shfl_xor(m, off, 16));
    float ex = __expf(acc - m);
    float s = ex;
#pragma unroll
    for (int off = 8; off >= 1; off >>= 1) s += __shfl_xor(s, off, 16);
    wsel[(size_t)row * 16 + e] = ex / s;
}

// ================= 256x256 GEMM — 1 barrier/tile, ph1 burst prefetch =================
// C = post(A @ Bt^T + bias). 8 waves (2Mx4N), BK=64, LDS 128KiB double-buffered.
// MODE 0: C = bf16(relu(acc+bias));  MODE 1: ... * wselp[row*16 + tn>>8].
// Swizzle byte ^= (row&7)<<4 via pre-swizzled global source + swizzled ds_read.
// Key schedule property: ALL 4 half-tiles of t+1 are issued at ph1 of tile t
// (nxt buffer is free from tile-t start), so the boundary vmcnt(0) waits on
// loads that are ~3 phases (~2000 cy) old — HBM latency fully hidden.
template<int MODE>
__global__ __launch_bounds__(512, 2)
void gemm256(const short* __restrict__ A, const short* __restrict__ Bt,
             const float* __restrict__ bias, const float* __restrict__ wselp,
             short* __restrict__ C, int M, int N, int K) {
    extern __shared__ __align__(16) short lds[];
    const int tid = threadIdx.x;
    const int w = tid >> 6, lane = tid & 63;
    const int wr = w >> 2, wc = w & 3;

    // bijective XCD swizzle (nwg % 8 == 0 for all our launches)
    const int gx = gridDim.x;
    const int b = blockIdx.y * gx + blockIdx.x;
    const int per = (gx * gridDim.y) >> 3;
    const int sb = (b & 7) * per + (b >> 3);
    const int bx = sb % gx, by = sb / gx;
    const int tm = by * 256, tn = bx * 256;

    const int rih = w * 8 + (lane >> 3);
    const int colel = (((lane & 7) ^ (lane >> 3)) << 3);
    const short* pA = A + (size_t)(tm + rih) * K + colel;
    const short* pB = Bt + (size_t)(tn + rih) * K + colel;
    const size_t rK64 = (size_t)64 * K, rK128 = (size_t)128 * K;
    short* const ldsw = lds + w * 512;

#define STG_A(buf, h, t) do { \
        const short* s_ = pA + (size_t)(h) * rK128 + (size_t)(t) * 64; \
        short* d_ = ldsw + (buf) * 32768 + (h) * 8192; \
        gload16(s_, d_); \
        gload16(s_ + rK64, d_ + 4096); } while (0)
#define STG_B(buf, h, t) do { \
        const short* s_ = pB + (size_t)(h) * rK128 + (size_t)(t) * 64; \
        short* d_ = ldsw + (buf) * 32768 + 16384 + (h) * 8192; \
        gload16(s_, d_); \
        gload16(s_ + rK64, d_ + 4096); } while (0)

    const int rA = lane & 15, q = lane >> 4;
    const int csw0 = ((q << 4)) ^ ((lane & 7) << 4);
    const int csw1 = (64 + (q << 4)) ^ ((lane & 7) << 4);
    const char* const ldsB_ = (const char*)lds;
    const int aBase0 = wr * 16384 + rA * 128;
    const int bBase0 = 32768 + (wc >> 1) * 16384 + ((wc & 1) * 64 + rA) * 128;

    f32x4 acc[8][4] = {};
    short8 a[4][2], b0[2][2], b1[2][2];
    const int nt = K >> 6;

    // prologue: tile0 (8 loads)
    STG_A(0, 0, 0); STG_A(0, 1, 0); STG_B(0, 0, 0); STG_B(0, 1, 0);
    WAITV0(); BAR();

    for (int t = 0; t < nt; ++t) {
        const int cur = t & 1, nxt = cur ^ 1;
        const char* pa = ldsB_ + cur * 65536 + aBase0;
        const char* pb = ldsB_ + cur * 65536 + bBase0;
        // ---- ph1: read a-lo + b0 ; burst-stage ALL of tile t+1 ; quad (lo,lo) ----
#pragma unroll
        for (int m = 0; m < 4; m++) {
            a[m][0] = *(const short8*)(pa + m * 2048 + csw0);
            a[m][1] = *(const short8*)(pa + m * 2048 + csw1);
        }
#pragma unroll
        for (int n = 0; n < 2; n++) {
            b0[n][0] = *(const short8*)(pb + n * 2048 + csw0);
            b0[n][1] = *(const short8*)(pb + n * 2048 + csw1);
        }
        if (t + 1 < nt) {
            STG_A(nxt, 0, t + 1); STG_A(nxt, 1, t + 1);
            STG_B(nxt, 0, t + 1); STG_B(nxt, 1, t + 1);
        }
        WAITL0(); SGB();
        __builtin_amdgcn_s_setprio(1);
#pragma unroll
        for (int m = 0; m < 4; m++)
#pragma unroll
            for (int n = 0; n < 2; n++) {
                acc[m][n] = __builtin_amdgcn_mfma_f32_16x16x32_bf16(a[m][0], b0[n][0], acc[m][n], 0, 0, 0);
                acc[m][n] = __builtin_amdgcn_mfma_f32_16x16x32_bf16(a[m][1], b0[n][1], acc[m][n], 0, 0, 0);
            }
        __builtin_amdgcn_s_setprio(0);
        // ---- ph2: read b1 ; quad (lo,hi) ----
#pragma unroll
        for (int n = 0; n < 2; n++) {
            b1[n][0] = *(const short8*)(pb + (2 + n) * 2048 + csw0);
            b1[n][1] = *(const short8*)(pb + (2 + n) * 2048 + csw1);
        }
        WAITL0(); SGB();
        __builtin_amdgcn_s_setprio(1);
#pragma unroll
        for (int m = 0; m < 4; m++)
#pragma unroll
            for (int n = 0; n < 2; n++) {
                acc[m][2 + n] = __builtin_amdgcn_mfma_f32_16x16x32_bf16(a[m][0], b1[n][0], acc[m][2 + n], 0, 0, 0);
                acc[m][2 + n] = __builtin_amdgcn_mfma_f32_16x16x32_bf16(a[m][1], b1[n][1], acc[m][2 + n], 0, 0, 0);
            }
        __builtin_amdgcn_s_setprio(0);
        // ---- ph3: read a-hi ; quad (hi,hi) ----
#pragma unroll
        for (int m = 0; m < 4; m++) {
            a[m][0] = *(const short8*)(pa + (4 + m) * 2048 + csw0);
            a[m][1] = *(const short8*)(pa + (4 + m) * 2048 + csw1);
        }
        WAITL0(); SGB();
        __builtin_amdgcn_s_setprio(1);
#pragma unroll
        for (int m = 0; m < 4; m++)
#pragma unroll
            for (int n = 0; n < 2; n++) {
                acc[4 + m][2 + n] = __builtin_amdgcn_mfma_f32_16x16x32_bf16(a[m][0], b1[n][0], acc[4 + m][2 + n], 0, 0, 0);
                acc[4 + m][2 + n] = __builtin_amdgcn_mfma_f32_16x16x32_bf16(a[m][1], b1[n][1], acc[4 + m][2 + n], 0, 0, 0);
            }
        __builtin_amdgcn_s_setprio(0);
        // ---- ph4: quad (hi,lo) ; single boundary barrier ----
        __builtin_amdgcn_s_setprio(1);
#pragma unroll
        for (int m = 0; m < 4; m++)
#pragma unroll
            for (int n = 0; n < 2; n++) {
                acc[4 + m][n] = __builtin_amdgcn_mfma_f32_16x16x32_bf16(a[m][0], b0[n][0], acc[4 + m][n], 0, 0, 0);
                acc[4 + m][n] = __builtin_amdgcn_mfma_f32_16x16x32_bf16(a[m][1], b0[n][1], acc[4 + m][n], 0, 0, 0);
            }
        __builtin_amdgcn_s_setprio(0);
        WAITV0();        // own stages drained (issued 3 phases ago — cheap)
        BAR();           // join: nxt resident everywhere; all reads of cur done
    }
#undef STG_A
#undef STG_B

    // ---- epilogue ----
    float biasv[4];
#pragma unroll
    for (int n = 0; n < 4; n++) biasv[n] = bias[tn + wc * 64 + n * 16 + rA];
    const int q4 = q * 4;
#pragma unroll
    for (int m = 0; m < 8; m++)
#pragma unroll
        for (int rr = 0; rr < 4; rr++) {
            const int row = tm + wr * 128 + m * 16 + q4 + rr;
            float ws = 1.f;
            if (MODE == 1) ws = wselp[(size_t)row * 16 + (tn >> 8)];
#pragma unroll
            for (int n = 0; n < 4; n++) {
                const int col = tn + wc * 64 + n * 16 + rA;
                float v = fmaxf(acc[m][n][rr] + biasv[n], 0.f);
                if (MODE == 1) v *= ws;
                C[(size_t)row * N + col] = f2b(v);
            }
        }
}

// ================= skinny fused GEMM2: out (+)= s_eh @ Bt2 (+ wsel@be2) =================
// s_eh[B,2048] bf16 (one 8-expert group), Bt2 base (row stride 4096) [32][2048 used].
// 4 waves x 128 rows/block, 2-phase double-buffered LDS staging. ~BW-bound.
__global__ __launch_bounds__(256)
void fuse_gemm(const short* __restrict__ Aeh, const short* __restrict__ Bt2,
               const float* __restrict__ wsel, const float* __restrict__ be2,
               float* __restrict__ out, int accflag) {
    __shared__ __align__(16) short sA[2][128 * 64];
    const int tid = threadIdx.x;
    const int w = tid >> 6, lane = tid & 63;
    const int tm = blockIdx.x * 128;
    const int rih = w * 8 + (lane >> 3);
    const int colel = (((lane & 7) ^ (lane >> 3)) << 3);
    const short* pA = Aeh + (size_t)(tm + rih) * 2048 + colel;
    const int rA = lane & 15;
    const int csw0 = (((lane >> 4) << 4)) ^ ((lane & 7) << 4);
    const int csw1 = (64 + ((lane >> 4) << 4)) ^ ((lane & 7) << 4);
    const short* pBg = Bt2 + (size_t)rA * 4096 + ((lane >> 4) << 3);

    f32x4 acc[2][2] = {};
#define STG_E(buf, t) do { \
        const short* s_ = pA + (size_t)(t) * 64; \
        short* d_ = &sA[buf][w * 512]; \
        gload16(s_, d_); \
        gload16(s_ + (size_t)32 * 2048, d_ + 2048); \
        gload16(s_ + (size_t)64 * 2048, d_ + 4096); \
        gload16(s_ + (size_t)96 * 2048, d_ + 6144); } while (0)

    const int NT = 32;          // 2048 / 64
    STG_E(0, 0);
    WAITV0(); BAR();
    for (int t = 0; t < NT; ++t) {
        const int cur = t & 1;
        if (t + 1 < NT) STG_E(cur ^ 1, t + 1);
        const char* pa = (const char*)&sA[cur][0] + (w * 32 + rA) * 128;
        short8 av[2][2], bv[2][2];
#pragma unroll
        for (int m = 0; m < 2; m++) {
            av[m][0] = *(const short8*)(pa + m * 2048 + csw0);
            av[m][1] = *(const short8*)(pa + m * 2048 + csw1);
        }
#pragma unroll
        for (int n = 0; n < 2; n++) {
            bv[n][0] = *(const short8*)(pBg + (size_t)n * 16 * 4096 + t * 64);
            bv[n][1] = *(const short8*)(pBg + (size_t)n * 16 * 4096 + t * 64 + 32);
        }
#pragma unroll
        for (int m = 0; m < 2; m++)
#pragma unroll
            for (int n = 0; n < 2; n++) {
                acc[m][n] = __builtin_amdgcn_mfma_f32_16x16x32_bf16(av[m][0], bv[n][0], acc[m][n], 0, 0, 0);
                acc[m][n] = __builtin_amdgcn_mfma_f32_16x16x32_bf16(av[m][1], bv[n][1], acc[m][n], 0, 0, 0);
            }
        WAITL0(); WAITV0(); BAR();
    }
#undef STG_E

    float be2v0[16], be2v1[16];
    if (!accflag) {
#pragma unroll
        for (int e = 0; e < 16; e++) {
            be2v0[e] = be2[e * 32 + rA];
            be2v1[e] = be2[e * 32 + 16 + rA];
        }
    }
    const int q4 = (lane >> 4) * 4;
#pragma unroll
    for (int m = 0; m < 2; m++)
#pragma unroll
        for (int rr = 0; rr < 4; rr++) {
            const int row = tm + w * 32 + m * 16 + q4 + rr;
            float v0 = acc[m][0][rr], v1 = acc[m][1][rr];
            if (!accflag) {
#pragma unroll
                for (int e = 0; e < 16; e++) {
                    float wv = wsel[(size_t)row * 16 + e];
                    v0 = fmaf(wv, be2v0[e], v0);
                    v1 = fmaf(wv, be2v1[e], v1);
                }
                out[(size_t)row * 32 + rA] = v0;
                out[(size_t)row * 32 + 16 + rA] = v1;
            } else {
                out[(size_t)row * 32 + rA] += v0;
                out[(size_t)row * 32 + 16 + rA] += v1;
            }
        }
}

extern "C" void kernel_launch(void* const* d_in, const int* in_sizes, int n_in,
                              void* d_out, int out_size, void* d_ws, size_t ws_size,
                              hipStream_t stream) {
    const float* obs = (const float*)d_in[0];
    const float* Wb0 = (const float*)d_in[1]; const float* bb0 = (const float*)d_in[2];
    const float* Wb1 = (const float*)d_in[3]; const float* bb1 = (const float*)d_in[4];
    const float* Wb2 = (const float*)d_in[5]; const float* bb2 = (const float*)d_in[6];
    const float* We1 = (const float*)d_in[7]; const float* be1 = (const float*)d_in[8];
    const float* We2 = (const float*)d_in[9]; const float* be2 = (const float*)d_in[10];
    const float* Ws0 = (const float*)d_in[11]; const float* bs0 = (const float*)d_in[12];
    const float* Ws1 = (const float*)d_in[13]; const float* bs1 = (const float*)d_in[14];
    const float* Ws2 = (const float*)d_in[15]; const float* bs2 = (const float*)d_in[16];

    const int B = 65536;
    char* ws = (char*)d_ws;
    size_t off = 0;
    auto alloc = [&](size_t bytes) { void* p = ws + off; off += (bytes + 255) & ~(size_t)255; return p; };
    short* obs_bf = (short*)alloc((size_t)B * 512 * 2);
    short* h1     = (short*)alloc((size_t)B * 1024 * 2);   // reused as s_eh (with h2)
    short* h2     = (short*)alloc((size_t)B * 1024 * 2);
    short* hbuf   = (short*)alloc((size_t)B * 512 * 2);
    short* s0     = (short*)alloc((size_t)B * 256 * 2);
    short* s1     = (short*)alloc((size_t)B * 128 * 2);
    float* wsel   = (float*)alloc((size_t)B * 16 * 4);
    short* Wb0t   = (short*)alloc((size_t)512 * 1024 * 2);
    short* Wb1t   = (short*)alloc((size_t)1024 * 1024 * 2);
    short* Wb2t   = (short*)alloc((size_t)1024 * 512 * 2);
    short* We1t   = (short*)alloc((size_t)16 * 512 * 256 * 2);
    short* Ws0t   = (short*)alloc((size_t)512 * 256 * 2);
    short* Ws1t   = (short*)alloc((size_t)256 * 128 * 2);
    short* Ws2t   = (short*)alloc((size_t)128 * 16 * 2);
    short* Bt2    = (short*)alloc((size_t)32 * 4096 * 2);
    short* s_eh = h1;   // B x 2048 bf16 = 256 MB, aliases h1+h2

    static int inited = 0;
    if (!inited) {
        hipFuncSetAttribute(reinterpret_cast<const void*>(gemm256<0>),
                            hipFuncAttributeMaxDynamicSharedMemorySize, 131072);
        hipFuncSetAttribute(reinterpret_cast<const void*>(gemm256<1>),
                            hipFuncAttributeMaxDynamicSharedMemorySize, 131072);
        inited = 1;
    }

    // --- preprocessing: casts / transposes / repack ---
    cast_bf16_kernel<<<(B * 512 / 8 + 255) / 256, 256, 0, stream>>>(obs, obs_bf, B * 512 / 8);
    transpose_cast_kernel<<<dim3((1024 * 512 / 8 + 255) / 256, 1), 256, 0, stream>>>(Wb0, Wb0t, 512, 1024, 1024 * 512 / 8);
    transpose_cast_kernel<<<dim3((1024 * 1024 / 8 + 255) / 256, 1), 256, 0, stream>>>(Wb1, Wb1t, 1024, 1024, 1024 * 1024 / 8);
    transpose_cast_kernel<<<dim3((512 * 1024 / 8 + 255) / 256, 1), 256, 0, stream>>>(Wb2, Wb2t, 1024, 512, 512 * 1024 / 8);
    transpose_cast_kernel<<<dim3((256 * 512 / 8 + 255) / 256, 16), 256, 0, stream>>>(We1, We1t, 512, 256, 256 * 512 / 8);
    transpose_cast_kernel<<<dim3((256 * 512 / 8 + 255) / 256, 1), 256, 0, stream>>>(Ws0, Ws0t, 512, 256, 256 * 512 / 8);
    transpose_cast_kernel<<<dim3((128 * 256 / 8 + 255) / 256, 1), 256, 0, stream>>>(Ws1, Ws1t, 256, 128, 128 * 256 / 8);
    transpose_cast_kernel<<<dim3((16 * 128 / 8 + 255) / 256, 1), 256, 0, stream>>>(Ws2, Ws2t, 128, 16, 16 * 128 / 8);
    repack_We2_kernel<<<64, 256, 0, stream>>>(We2, Bt2);

    // --- selector chain ---
    gemm256<0><<<dim3(1, B / 256), 512, 131072, stream>>>(obs_bf, Ws0t, bs0, nullptr, s0, B, 256, 512);
    gemm_bt_bias_relu<<<dim3(1, B / 128), 256, 0, stream>>>(s0, Ws1t, bs1, s1, B, 128, 256);
    selector_softmax<<<B / 16, 256, 0, stream>>>(s1, Ws2t, bs2, wsel);

    // --- backbone ---
    gemm256<0><<<dim3(4, B / 256), 512, 131072, stream>>>(obs_bf, Wb0t, bb0, nullptr, h1, B, 1024, 512);
    gemm256<0><<<dim3(4, B / 256), 512, 131072, stream>>>(h1, Wb1t, bb1, nullptr, h2, B, 1024, 1024);
    gemm256<0><<<dim3(2, B / 256), 512, 131072, stream>>>(h2, Wb2t, bb2, nullptr, hbuf, B, 512, 1024);

    // --- experts: 2 groups of 8; eh big-GEMM (wsel folded) + skinny fuse ---
    for (int g = 0; g < 2; ++g) {
        gemm256<1><<<dim3(8, B / 256), 512, 131072, stream>>>(
            hbuf, We1t + (size_t)g * 8 * 256 * 512, be1 + g * 2048, wsel + g * 8,
            s_eh, B, 2048, 512);
        fuse_gemm<<<B / 128, 256, 0, stream>>>(
            s_eh, Bt2 + g * 2048, wsel, be2, (float*)d_out, g);
    }
}

// Round 5
// 1033.117 us; speedup vs baseline: 1.9144x; 1.0811x over previous
//
#include <hip/hip_runtime.h>
#include <hip/hip_bf16.h>
#include <stdint.h>

typedef __attribute__((ext_vector_type(8))) short short8;
typedef __attribute__((ext_vector_type(4))) float f32x4;

__device__ __forceinline__ float b2f(short s) {
    union { unsigned u; float f; } v; v.u = ((unsigned)(unsigned short)s) << 16; return v.f;
}
__device__ __forceinline__ short f2b(float f) {
    union { float f; unsigned u; } v; v.f = f;
    unsigned r = (v.u + 0x7FFF + ((v.u >> 16) & 1)) >> 16;
    return (short)r;
}

// async global->LDS, 16B per lane. LDS dest is wave-uniform base + lane*16.
__device__ __forceinline__ void gload16(const void* g, void* l) {
    __builtin_amdgcn_global_load_lds(
        (const __attribute__((address_space(1))) void*)(uintptr_t)g,
        (__attribute__((address_space(3))) void*)(uintptr_t)l,
        16, 0, 0);
}

#define BAR()    asm volatile("s_barrier" ::: "memory")
#define WAITV0() asm volatile("s_waitcnt vmcnt(0)" ::: "memory")
#define WAITL0() asm volatile("s_waitcnt lgkmcnt(0)" ::: "memory")
#define SGB()    __builtin_amdgcn_sched_barrier(0)

// ---------------- cast fp32 -> bf16 (8 elems/thread) ----------------
__global__ __launch_bounds__(256) void cast_bf16_kernel(
    const float* __restrict__ src, short* __restrict__ dst, int n8) {
    int i = blockIdx.x * 256 + threadIdx.x;
    if (i >= n8) return;
    const float4* s = (const float4*)src + (size_t)i * 2;
    float4 x0 = s[0], x1 = s[1];
    short8 o;
    o[0] = f2b(x0.x); o[1] = f2b(x0.y); o[2] = f2b(x0.z); o[3] = f2b(x0.w);
    o[4] = f2b(x1.x); o[5] = f2b(x1.y); o[6] = f2b(x1.z); o[7] = f2b(x1.w);
    *((short8*)dst + i) = o;
}

// ---------- transpose-cast W[K,N] f32 -> Wt[N,K] bf16 (8 k per thread) ----------
__global__ __launch_bounds__(256) void transpose_cast_kernel(
    const float* __restrict__ W, short* __restrict__ Wt, int K, int N, int total) {
    int t = blockIdx.x * 256 + threadIdx.x;
    if (t >= total) return;
    const float* src = W + (size_t)blockIdx.y * K * N;
    short* dst = Wt + (size_t)blockIdx.y * K * N;
    int n = t % N;
    int k0 = (t / N) * 8;
    short8 o;
#pragma unroll
    for (int i = 0; i < 8; i++) o[i] = f2b(src[(size_t)(k0 + i) * N + n]);
    *(short8*)(dst + (size_t)n * K + k0) = o;
}

// ---------------- generic C = relu(A @ Bt^T + bias), bf16 out ----------------
// (kept for selector layer1 only: N=128)
__global__ __launch_bounds__(256, 3)
void gemm_bt_bias_relu(const short* __restrict__ A, const short* __restrict__ Bt,
                       const float* __restrict__ bias, short* __restrict__ C,
                       int M, int N, int K) {
    __shared__ __align__(16) short As[128 * 32];
    __shared__ __align__(16) short Bs[128 * 32];
    const int tid = threadIdx.x;
    const int w = tid >> 6, lane = tid & 63;
    const int tm = blockIdx.y * 128, tn = blockIdx.x * 128;
    const int wm = (w & 1) * 64, wn = (w >> 1) * 64;
    const int r = lane & 15, q = lane >> 4, qk = q * 8;

    const int c0 = w * 2, c1 = w * 2 + 1;
    const int srow0 = c0 * 16 + (lane >> 2);
    const int srow1 = c1 * 16 + (lane >> 2);
    const int skk = (lane & 3) * 8;
    const short* gA0 = A + (size_t)(tm + srow0) * K + skk;
    const short* gA1 = A + (size_t)(tm + srow1) * K + skk;
    const short* gB0 = Bt + (size_t)(tn + srow0) * K + skk;
    const short* gB1 = Bt + (size_t)(tn + srow1) * K + skk;
    short* lA0 = &As[c0 * 512]; short* lA1 = &As[c1 * 512];
    short* lB0 = &Bs[c0 * 512]; short* lB1 = &Bs[c1 * 512];

    f32x4 acc[4][4] = {};
    for (int k0 = 0; k0 < K; k0 += 32) {
        gload16(gA0 + k0, lA0);
        gload16(gA1 + k0, lA1);
        gload16(gB0 + k0, lB0);
        gload16(gB1 + k0, lB1);
        __syncthreads();
        short8 a[4], b[4];
#pragma unroll
        for (int i = 0; i < 4; i++) a[i] = *(const short8*)&As[(wm + i * 16 + r) * 32 + qk];
#pragma unroll
        for (int j = 0; j < 4; j++) b[j] = *(const short8*)&Bs[(wn + j * 16 + r) * 32 + qk];
#pragma unroll
        for (int i = 0; i < 4; i++)
#pragma unroll
            for (int j = 0; j < 4; j++)
                acc[i][j] = __builtin_amdgcn_mfma_f32_16x16x32_bf16(a[i], b[j], acc[i][j], 0, 0, 0);
        __syncthreads();
    }
#pragma unroll
    for (int j = 0; j < 4; j++) {
        int col = tn + wn + j * 16 + r;
        float bj = bias[col];
#pragma unroll
        for (int i = 0; i < 4; i++)
#pragma unroll
            for (int rr = 0; rr < 4; rr++) {
                int row = tm + wm + i * 16 + q * 4 + rr;
                float v = fmaxf(acc[i][j][rr] + bj, 0.f);
                C[(size_t)row * N + col] = f2b(v);
            }
    }
}

// ---------------- selector last layer + softmax ----------------
__global__ __launch_bounds__(256)
void selector_softmax(const short* __restrict__ s1, const short* __restrict__ Ws2t,
                      const float* __restrict__ bs2, float* __restrict__ wsel) {
    int tid = threadIdx.x;
    int row = blockIdx.x * 16 + (tid >> 4);
    int e = tid & 15;
    const short8* a = (const short8*)(s1 + (size_t)row * 128);
    const short8* b = (const short8*)(Ws2t + (size_t)e * 128);
    float acc = bs2[e];
#pragma unroll
    for (int kk = 0; kk < 16; ++kk) {
        short8 av = a[kk], bv = b[kk];
#pragma unroll
        for (int i = 0; i < 8; i++) acc = fmaf(b2f(av[i]), b2f(bv[i]), acc);
    }
    float m = acc;
#pragma unroll
    for (int off = 8; off >= 1; off >>= 1) m = fmaxf(m, __shfl_xor(m, off, 16));
    float ex = __expf(acc - m);
    float s = ex;
#pragma unroll
    for (int off = 8; off >= 1; off >>= 1) s += __shfl_xor(s, off, 16);
    wsel[(size_t)row * 16 + e] = ex / s;
}

// ---------------- out init: out[b,a] = sum_e wsel[b,e]*be2[e,a] ----------------
__global__ __launch_bounds__(256)
void out_init_kernel(const float* __restrict__ wsel, const float* __restrict__ be2,
                     float* __restrict__ out) {
    int i = blockIdx.x * 256 + threadIdx.x;      // over B*32
    int row = i >> 5, a = i & 31;
    const float* wr = wsel + (size_t)row * 16;
    float acc = 0.f;
#pragma unroll
    for (int e = 0; e < 16; e++) acc = fmaf(wr[e], be2[e * 32 + a], acc);
    out[i] = acc;
}

// ---------------- reduce: out[i][a] += sum_bx partial[by][bx][r][a] ----------------
__global__ __launch_bounds__(256)
void reduce_kernel(const float* __restrict__ partial, float* __restrict__ out) {
    int t = blockIdx.x * 256 + threadIdx.x;      // B * 8 threads
    int a4 = t & 7, i = t >> 3;
    int by = i >> 8, r = i & 255;
    const float* p = partial + (size_t)by * 16 * 8192 + r * 32 + a4 * 4;
    f32x4 s = *(const f32x4*)(out + (size_t)i * 32 + a4 * 4);
#pragma unroll
    for (int bx = 0; bx < 16; bx++) s += *(const f32x4*)(p + (size_t)bx * 8192);
    *(f32x4*)(out + (size_t)i * 32 + a4 * 4) = s;
}

// ================= 256x256 GEMM — 1 barrier/tile, ph1 burst prefetch =================
// 8 waves (2Mx4N), BK=64, LDS 128KiB double-buffered, swizzle byte ^= (row&7)<<4.
// MODE 0: C = bf16(relu(acc+bias))
// MODE 1: C = bf16(relu(acc+bias) * wselp[row*16 + tn>>8])
// MODE 2: expert fused — eh = relu(acc+be1)*wsel -> LDS (swizzled) -> GEMM2 vs
//         We2t[e] (K=256,N=32) -> f32 partial[by][e][256][32]  (C unused)
template<int MODE>
__global__ __launch_bounds__(512, 2)
void gemm256(const short* __restrict__ A, const short* __restrict__ Bt,
             const float* __restrict__ bias, const float* __restrict__ wselp,
             const short* __restrict__ W2, short* __restrict__ C,
             float* __restrict__ pout, int M, int N, int K) {
    extern __shared__ __align__(16) short lds[];
    const int tid = threadIdx.x;
    const int w = tid >> 6, lane = tid & 63;
    const int wr = w >> 2, wc = w & 3;

    // bijective XCD swizzle (nwg % 8 == 0 for all our launches)
    const int gx = gridDim.x;
    const int b = blockIdx.y * gx + blockIdx.x;
    const int per = (gx * gridDim.y) >> 3;
    const int sb = (b & 7) * per + (b >> 3);
    const int bx = sb % gx, by = sb / gx;
    const int tm = by * 256, tn = bx * 256;

    const int rih = w * 8 + (lane >> 3);
    const int colel = (((lane & 7) ^ (lane >> 3)) << 3);
    const short* pA = A + (size_t)(tm + rih) * K + colel;
    const short* pB = Bt + (size_t)(tn + rih) * K + colel;
    const size_t rK64 = (size_t)64 * K, rK128 = (size_t)128 * K;
    short* const ldsw = lds + w * 512;

#define STG_A(buf, h, t) do { \
        const short* s_ = pA + (size_t)(h) * rK128 + (size_t)(t) * 64; \
        short* d_ = ldsw + (buf) * 32768 + (h) * 8192; \
        gload16(s_, d_); \
        gload16(s_ + rK64, d_ + 4096); } while (0)
#define STG_B(buf, h, t) do { \
        const short* s_ = pB + (size_t)(h) * rK128 + (size_t)(t) * 64; \
        short* d_ = ldsw + (buf) * 32768 + 16384 + (h) * 8192; \
        gload16(s_, d_); \
        gload16(s_ + rK64, d_ + 4096); } while (0)

    const int rA = lane & 15, q = lane >> 4;
    const int csw0 = ((q << 4)) ^ ((lane & 7) << 4);
    const int csw1 = (64 + (q << 4)) ^ ((lane & 7) << 4);
    const char* const ldsB_ = (const char*)lds;
    const int aBase0 = wr * 16384 + rA * 128;
    const int bBase0 = 32768 + (wc >> 1) * 16384 + ((wc & 1) * 64 + rA) * 128;

    f32x4 acc[8][4] = {};
    short8 a[4][2], b0[2][2], b1[2][2];
    const int nt = K >> 6;

    // prologue: tile0 (8 loads)
    STG_A(0, 0, 0); STG_A(0, 1, 0); STG_B(0, 0, 0); STG_B(0, 1, 0);
    WAITV0(); BAR();

    for (int t = 0; t < nt; ++t) {
        const int cur = t & 1, nxt = cur ^ 1;
        const char* pa = ldsB_ + cur * 65536 + aBase0;
        const char* pb = ldsB_ + cur * 65536 + bBase0;
        // ---- ph1: read a-lo + b0 ; burst-stage ALL of tile t+1 ; quad (lo,lo) ----
#pragma unroll
        for (int m = 0; m < 4; m++) {
            a[m][0] = *(const short8*)(pa + m * 2048 + csw0);
            a[m][1] = *(const short8*)(pa + m * 2048 + csw1);
        }
#pragma unroll
        for (int n = 0; n < 2; n++) {
            b0[n][0] = *(const short8*)(pb + n * 2048 + csw0);
            b0[n][1] = *(const short8*)(pb + n * 2048 + csw1);
        }
        if (t + 1 < nt) {
            STG_A(nxt, 0, t + 1); STG_A(nxt, 1, t + 1);
            STG_B(nxt, 0, t + 1); STG_B(nxt, 1, t + 1);
        }
        WAITL0(); SGB();
        __builtin_amdgcn_s_setprio(1);
#pragma unroll
        for (int m = 0; m < 4; m++)
#pragma unroll
            for (int n = 0; n < 2; n++) {
                acc[m][n] = __builtin_amdgcn_mfma_f32_16x16x32_bf16(a[m][0], b0[n][0], acc[m][n], 0, 0, 0);
                acc[m][n] = __builtin_amdgcn_mfma_f32_16x16x32_bf16(a[m][1], b0[n][1], acc[m][n], 0, 0, 0);
            }
        __builtin_amdgcn_s_setprio(0);
        // ---- ph2: read b1 ; quad (lo,hi) ----
#pragma unroll
        for (int n = 0; n < 2; n++) {
            b1[n][0] = *(const short8*)(pb + (2 + n) * 2048 + csw0);
            b1[n][1] = *(const short8*)(pb + (2 + n) * 2048 + csw1);
        }
        WAITL0(); SGB();
        __builtin_amdgcn_s_setprio(1);
#pragma unroll
        for (int m = 0; m < 4; m++)
#pragma unroll
            for (int n = 0; n < 2; n++) {
                acc[m][2 + n] = __builtin_amdgcn_mfma_f32_16x16x32_bf16(a[m][0], b1[n][0], acc[m][2 + n], 0, 0, 0);
                acc[m][2 + n] = __builtin_amdgcn_mfma_f32_16x16x32_bf16(a[m][1], b1[n][1], acc[m][2 + n], 0, 0, 0);
            }
        __builtin_amdgcn_s_setprio(0);
        // ---- ph3: read a-hi ; quad (hi,hi) ----
#pragma unroll
        for (int m = 0; m < 4; m++) {
            a[m][0] = *(const short8*)(pa + (4 + m) * 2048 + csw0);
            a[m][1] = *(const short8*)(pa + (4 + m) * 2048 + csw1);
        }
        WAITL0(); SGB();
        __builtin_amdgcn_s_setprio(1);
#pragma unroll
        for (int m = 0; m < 4; m++)
#pragma unroll
            for (int n = 0; n < 2; n++) {
                acc[4 + m][2 + n] = __builtin_amdgcn_mfma_f32_16x16x32_bf16(a[m][0], b1[n][0], acc[4 + m][2 + n], 0, 0, 0);
                acc[4 + m][2 + n] = __builtin_amdgcn_mfma_f32_16x16x32_bf16(a[m][1], b1[n][1], acc[4 + m][2 + n], 0, 0, 0);
            }
        __builtin_amdgcn_s_setprio(0);
        // ---- ph4: quad (hi,lo) ; single boundary barrier ----
        __builtin_amdgcn_s_setprio(1);
#pragma unroll
        for (int m = 0; m < 4; m++)
#pragma unroll
            for (int n = 0; n < 2; n++) {
                acc[4 + m][n] = __builtin_amdgcn_mfma_f32_16x16x32_bf16(a[m][0], b0[n][0], acc[4 + m][n], 0, 0, 0);
                acc[4 + m][n] = __builtin_amdgcn_mfma_f32_16x16x32_bf16(a[m][1], b0[n][1], acc[4 + m][n], 0, 0, 0);
            }
        __builtin_amdgcn_s_setprio(0);
        WAITV0();        // own stages drained (issued 3 phases ago — cheap)
        BAR();           // join: nxt resident everywhere; all reads of cur done
    }
#undef STG_A
#undef STG_B

    const int q4 = q * 4;
    float biasv[4];
#pragma unroll
    for (int n = 0; n < 4; n++) biasv[n] = bias[tn + wc * 64 + n * 16 + rA];

    if (MODE == 2) {
        // ---- eh -> LDS (bf16, wsel-scaled, XOR-swizzled), whole 128KB ----
        const int e = tn >> 8;
        char* ldsc = (char*)lds;
#pragma unroll
        for (int m = 0; m < 8; m++)
#pragma unroll
            for (int rr = 0; rr < 4; rr++) {
                const int row = wr * 128 + m * 16 + q4 + rr;          // 0..255 local
                const float ws = wselp[(size_t)(tm + row) * 16 + e];
#pragma unroll
                for (int n = 0; n < 4; n++) {
                    const int col = wc * 64 + n * 16 + rA;            // 0..255 local
                    const float v = fmaxf(acc[m][n][rr] + biasv[n], 0.f) * ws;
                    *(short*)(ldsc + row * 512 + ((col * 2) ^ ((row & 7) << 4))) = f2b(v);
                }
            }
        WAITL0(); BAR();
        // ---- GEMM2 partial: eh(256x256) @ We2t[e](32x256)^T ----
        f32x4 g2[2][2] = {};
#pragma unroll
        for (int k2 = 0; k2 < 8; ++k2) {
            short8 a2[2], b2[2];
#pragma unroll
            for (int m2 = 0; m2 < 2; m2++) {
                const int row = w * 32 + m2 * 16 + rA;
                a2[m2] = *(const short8*)(ldsc + row * 512 + ((k2 * 64 + q * 16) ^ ((row & 7) << 4)));
            }
#pragma unroll
            for (int n2 = 0; n2 < 2; n2++)
                b2[n2] = *(const short8*)(W2 + (size_t)(e * 32 + n2 * 16 + rA) * 256 + k2 * 32 + q * 8);
#pragma unroll
            for (int m2 = 0; m2 < 2; m2++)
#pragma unroll
                for (int n2 = 0; n2 < 2; n2++)
                    g2[m2][n2] = __builtin_amdgcn_mfma_f32_16x16x32_bf16(a2[m2], b2[n2], g2[m2][n2], 0, 0, 0);
        }
        // ---- store f32 partial [by][e][256][32] ----
        float* pp = pout + ((size_t)(tm >> 8) * 16 + e) * 8192;
#pragma unroll
        for (int m2 = 0; m2 < 2; m2++)
#pragma unroll
            for (int rr = 0; rr < 4; rr++) {
                const int row = w * 32 + m2 * 16 + q4 + rr;
#pragma unroll
                for (int n2 = 0; n2 < 2; n2++)
                    pp[row * 32 + n2 * 16 + rA] = g2[m2][n2][rr];
            }
        return;
    }

    // ---- MODE 0/1 epilogue ----
#pragma unroll
    for (int m = 0; m < 8; m++)
#pragma unroll
        for (int rr = 0; rr < 4; rr++) {
            const int row = tm + wr * 128 + m * 16 + q4 + rr;
            float ws = 1.f;
            if (MODE == 1) ws = wselp[(size_t)row * 16 + (tn >> 8)];
#pragma unroll
            for (int n = 0; n < 4; n++) {
                const int col = tn + wc * 64 + n * 16 + rA;
                float v = fmaxf(acc[m][n][rr] + biasv[n], 0.f);
                if (MODE == 1) v *= ws;
                C[(size_t)row * N + col] = f2b(v);
            }
        }
}

extern "C" void kernel_launch(void* const* d_in, const int* in_sizes, int n_in,
                              void* d_out, int out_size, void* d_ws, size_t ws_size,
                              hipStream_t stream) {
    const float* obs = (const float*)d_in[0];
    const float* Wb0 = (const float*)d_in[1]; const float* bb0 = (const float*)d_in[2];
    const float* Wb1 = (const float*)d_in[3]; const float* bb1 = (const float*)d_in[4];
    const float* Wb2 = (const float*)d_in[5]; const float* bb2 = (const float*)d_in[6];
    const float* We1 = (const float*)d_in[7]; const float* be1 = (const float*)d_in[8];
    const float* We2 = (const float*)d_in[9]; const float* be2 = (const float*)d_in[10];
    const float* Ws0 = (const float*)d_in[11]; const float* bs0 = (const float*)d_in[12];
    const float* Ws1 = (const float*)d_in[13]; const float* bs1 = (const float*)d_in[14];
    const float* Ws2 = (const float*)d_in[15]; const float* bs2 = (const float*)d_in[16];

    const int B = 65536;
    char* ws = (char*)d_ws;
    size_t off = 0;
    auto alloc = [&](size_t bytes) { void* p = ws + off; off += (bytes + 255) & ~(size_t)255; return p; };
    short* obs_bf = (short*)alloc((size_t)B * 512 * 2);
    short* h1     = (short*)alloc((size_t)B * 1024 * 2);   // dead after Wb1; reused as partial
    short* h2     = (short*)alloc((size_t)B * 1024 * 2);   // dead after Wb2; partial tail
    short* hbuf   = (short*)alloc((size_t)B * 512 * 2);
    short* s0     = (short*)alloc((size_t)B * 256 * 2);
    short* s1     = (short*)alloc((size_t)B * 128 * 2);
    float* wsel   = (float*)alloc((size_t)B * 16 * 4);
    short* Wb0t   = (short*)alloc((size_t)512 * 1024 * 2);
    short* Wb1t   = (short*)alloc((size_t)1024 * 1024 * 2);
    short* Wb2t   = (short*)alloc((size_t)1024 * 512 * 2);
    short* We1t   = (short*)alloc((size_t)16 * 512 * 256 * 2);
    short* We2t   = (short*)alloc((size_t)16 * 256 * 32 * 2);
    short* Ws0t   = (short*)alloc((size_t)512 * 256 * 2);
    short* Ws1t   = (short*)alloc((size_t)256 * 128 * 2);
    short* Ws2t   = (short*)alloc((size_t)128 * 16 * 2);
    // partial [256 by][16 e][256 r][32 a] f32 = 134.2 MB, aliases dead h1(+h2 head)
    float* partial = (float*)h1;

    static int inited = 0;
    if (!inited) {
        hipFuncSetAttribute(reinterpret_cast<const void*>(gemm256<0>),
                            hipFuncAttributeMaxDynamicSharedMemorySize, 131072);
        hipFuncSetAttribute(reinterpret_cast<const void*>(gemm256<2>),
                            hipFuncAttributeMaxDynamicSharedMemorySize, 131072);
        inited = 1;
    }

    // --- preprocessing: casts / transposes ---
    cast_bf16_kernel<<<(B * 512 / 8 + 255) / 256, 256, 0, stream>>>(obs, obs_bf, B * 512 / 8);
    transpose_cast_kernel<<<dim3((1024 * 512 / 8 + 255) / 256, 1), 256, 0, stream>>>(Wb0, Wb0t, 512, 1024, 1024 * 512 / 8);
    transpose_cast_kernel<<<dim3((1024 * 1024 / 8 + 255) / 256, 1), 256, 0, stream>>>(Wb1, Wb1t, 1024, 1024, 1024 * 1024 / 8);
    transpose_cast_kernel<<<dim3((512 * 1024 / 8 + 255) / 256, 1), 256, 0, stream>>>(Wb2, Wb2t, 1024, 512, 512 * 1024 / 8);
    transpose_cast_kernel<<<dim3((256 * 512 / 8 + 255) / 256, 16), 256, 0, stream>>>(We1, We1t, 512, 256, 256 * 512 / 8);
    transpose_cast_kernel<<<dim3((32 * 256 / 8 + 255) / 256, 16), 256, 0, stream>>>(We2, We2t, 256, 32, 32 * 256 / 8);
    transpose_cast_kernel<<<dim3((256 * 512 / 8 + 255) / 256, 1), 256, 0, stream>>>(Ws0, Ws0t, 512, 256, 256 * 512 / 8);
    transpose_cast_kernel<<<dim3((128 * 256 / 8 + 255) / 256, 1), 256, 0, stream>>>(Ws1, Ws1t, 256, 128, 128 * 256 / 8);
    transpose_cast_kernel<<<dim3((16 * 128 / 8 + 255) / 256, 1), 256, 0, stream>>>(Ws2, Ws2t, 128, 16, 16 * 128 / 8);

    // --- selector chain ---
    gemm256<0><<<dim3(1, B / 256), 512, 131072, stream>>>(obs_bf, Ws0t, bs0, nullptr, nullptr, s0, nullptr, B, 256, 512);
    gemm_bt_bias_relu<<<dim3(1, B / 128), 256, 0, stream>>>(s0, Ws1t, bs1, s1, B, 128, 256);
    selector_softmax<<<B / 16, 256, 0, stream>>>(s1, Ws2t, bs2, wsel);
    out_init_kernel<<<B * 32 / 256, 256, 0, stream>>>(wsel, be2, (float*)d_out);

    // --- backbone ---
    gemm256<0><<<dim3(4, B / 256), 512, 131072, stream>>>(obs_bf, Wb0t, bb0, nullptr, nullptr, h1, nullptr, B, 1024, 512);
    gemm256<0><<<dim3(4, B / 256), 512, 131072, stream>>>(h1, Wb1t, bb1, nullptr, nullptr, h2, nullptr, B, 1024, 1024);
    gemm256<0><<<dim3(2, B / 256), 512, 131072, stream>>>(h2, Wb2t, bb2, nullptr, nullptr, hbuf, nullptr, B, 512, 1024);

    // --- experts: single fused dispatch (GEMM1 + in-block GEMM2 -> partials) ---
    gemm256<2><<<dim3(16, B / 256), 512, 131072, stream>>>(
        hbuf, We1t, be1, wsel, We2t, nullptr, partial, B, 4096, 512);
    reduce_kernel<<<B * 8 / 256, 256, 0, stream>>>(partial, (float*)d_out);
}

// Round 6
// 1007.869 us; speedup vs baseline: 1.9624x; 1.0251x over previous
//
#include <hip/hip_runtime.h>
#include <hip/hip_bf16.h>
#include <stdint.h>

typedef __attribute__((ext_vector_type(8))) short short8;
typedef __attribute__((ext_vector_type(4))) float f32x4;

__device__ __forceinline__ float b2f(short s) {
    union { unsigned u; float f; } v; v.u = ((unsigned)(unsigned short)s) << 16; return v.f;
}
__device__ __forceinline__ short f2b(float f) {
    union { float f; unsigned u; } v; v.f = f;
    unsigned r = (v.u + 0x7FFF + ((v.u >> 16) & 1)) >> 16;
    return (short)r;
}

// async global->LDS, 16B per lane. LDS dest is wave-uniform base + lane*16.
__device__ __forceinline__ void gload16(const void* g, void* l) {
    __builtin_amdgcn_global_load_lds(
        (const __attribute__((address_space(1))) void*)(uintptr_t)g,
        (__attribute__((address_space(3))) void*)(uintptr_t)l,
        16, 0, 0);
}

#define BAR()    asm volatile("s_barrier" ::: "memory")
#define WAITV0() asm volatile("s_waitcnt vmcnt(0)" ::: "memory")

// ---------------- cast fp32 -> bf16 (8 elems/thread) ----------------
__global__ __launch_bounds__(256) void cast_bf16_kernel(
    const float* __restrict__ src, short* __restrict__ dst, int n8) {
    int i = blockIdx.x * 256 + threadIdx.x;
    if (i >= n8) return;
    const float4* s = (const float4*)src + (size_t)i * 2;
    float4 x0 = s[0], x1 = s[1];
    short8 o;
    o[0] = f2b(x0.x); o[1] = f2b(x0.y); o[2] = f2b(x0.z); o[3] = f2b(x0.w);
    o[4] = f2b(x1.x); o[5] = f2b(x1.y); o[6] = f2b(x1.z); o[7] = f2b(x1.w);
    *((short8*)dst + i) = o;
}

// ---------- transpose-cast W[K,N] f32 -> Wt[N,K] bf16 (8 k per thread) ----------
__global__ __launch_bounds__(256) void transpose_cast_kernel(
    const float* __restrict__ W, short* __restrict__ Wt, int K, int N, int total) {
    int t = blockIdx.x * 256 + threadIdx.x;
    if (t >= total) return;
    const float* src = W + (size_t)blockIdx.y * K * N;
    short* dst = Wt + (size_t)blockIdx.y * K * N;
    int n = t % N;
    int k0 = (t / N) * 8;
    short8 o;
#pragma unroll
    for (int i = 0; i < 8; i++) o[i] = f2b(src[(size_t)(k0 + i) * N + n]);
    *(short8*)(dst + (size_t)n * K + k0) = o;
}

// ---------------- fused selector: s0 -> s1 -> logits -> softmax -> wsel ----------------
// s0[B,256] bf16, Ws1t[128,256] bf16, Ws2t[16,128] bf16. 128 rows/block, 4 waves.
__global__ __launch_bounds__(256, 3)
void sel_fused(const short* __restrict__ s0, const short* __restrict__ Ws1t,
               const float* __restrict__ bs1, const short* __restrict__ Ws2t,
               const float* __restrict__ bs2, float* __restrict__ wsel) {
    __shared__ __align__(16) short As[128 * 32];
    __shared__ __align__(16) short Bs[128 * 32];
    __shared__ __align__(16) short s1l[128 * 136];
    const int tid = threadIdx.x;
    const int w = tid >> 6, lane = tid & 63;
    const int tm = blockIdx.x * 128;
    const int wm = (w & 1) * 64, wn = (w >> 1) * 64;
    const int r = lane & 15, q = lane >> 4, qk = q * 8;

    const int c0 = w * 2, c1 = w * 2 + 1;
    const int srow0 = c0 * 16 + (lane >> 2);
    const int srow1 = c1 * 16 + (lane >> 2);
    const int skk = (lane & 3) * 8;
    const short* gA0 = s0 + (size_t)(tm + srow0) * 256 + skk;
    const short* gA1 = s0 + (size_t)(tm + srow1) * 256 + skk;
    const short* gB0 = Ws1t + (size_t)srow0 * 256 + skk;
    const short* gB1 = Ws1t + (size_t)srow1 * 256 + skk;
    short* lA0 = &As[c0 * 512]; short* lA1 = &As[c1 * 512];
    short* lB0 = &Bs[c0 * 512]; short* lB1 = &Bs[c1 * 512];

    f32x4 acc[4][4] = {};
    for (int k0 = 0; k0 < 256; k0 += 32) {
        gload16(gA0 + k0, lA0);
        gload16(gA1 + k0, lA1);
        gload16(gB0 + k0, lB0);
        gload16(gB1 + k0, lB1);
        __syncthreads();
        short8 a[4], b[4];
#pragma unroll
        for (int i = 0; i < 4; i++) a[i] = *(const short8*)&As[(wm + i * 16 + r) * 32 + qk];
#pragma unroll
        for (int j = 0; j < 4; j++) b[j] = *(const short8*)&Bs[(wn + j * 16 + r) * 32 + qk];
#pragma unroll
        for (int i = 0; i < 4; i++)
#pragma unroll
            for (int j = 0; j < 4; j++)
                acc[i][j] = __builtin_amdgcn_mfma_f32_16x16x32_bf16(a[i], b[j], acc[i][j], 0, 0, 0);
        __syncthreads();
    }
    // s1 tile (relu+bias) -> padded LDS
#pragma unroll
    for (int j = 0; j < 4; j++) {
        int col = wn + j * 16 + r;
        float bj = bs1[col];
#pragma unroll
        for (int i = 0; i < 4; i++)
#pragma unroll
            for (int rr = 0; rr < 4; rr++) {
                int row = wm + i * 16 + q * 4 + rr;
                s1l[row * 136 + col] = f2b(fmaxf(acc[i][j][rr] + bj, 0.f));
            }
    }
    __syncthreads();
    // GEMM3: rows w*32..+32 of s1 @ Ws2t[16,128] -> logits; softmax over 16 lanes
    f32x4 acc3[2] = {};
#pragma unroll
    for (int k3 = 0; k3 < 4; ++k3) {
        short8 b3 = *(const short8*)(Ws2t + (size_t)r * 128 + k3 * 32 + qk);
#pragma unroll
        for (int m2 = 0; m2 < 2; m2++) {
            short8 a3 = *(const short8*)&s1l[(w * 32 + m2 * 16 + r) * 136 + k3 * 32 + qk];
            acc3[m2] = __builtin_amdgcn_mfma_f32_16x16x32_bf16(a3, b3, acc3[m2], 0, 0, 0);
        }
    }
    float bse = bs2[r];
#pragma unroll
    for (int m2 = 0; m2 < 2; m2++)
#pragma unroll
        for (int rr = 0; rr < 4; rr++) {
            int row = tm + w * 32 + m2 * 16 + q * 4 + rr;
            float v = acc3[m2][rr] + bse;
            float m = v;
#pragma unroll
            for (int off = 8; off >= 1; off >>= 1) m = fmaxf(m, __shfl_xor(m, off, 16));
            float ex = __expf(v - m);
            float s = ex;
#pragma unroll
            for (int off = 8; off >= 1; off >>= 1) s += __shfl_xor(s, off, 16);
            wsel[(size_t)row * 16 + r] = ex / s;
        }
}

// ---------------- out init: out[b,a] = sum_e wsel[b,e]*be2[e,a] ----------------
__global__ __launch_bounds__(256)
void out_init_kernel(const float* __restrict__ wsel, const float* __restrict__ be2,
                     float* __restrict__ out) {
    int i = blockIdx.x * 256 + threadIdx.x;      // over B*32
    int row = i >> 5, a = i & 31;
    const float* wr = wsel + (size_t)row * 16;
    float acc = 0.f;
#pragma unroll
    for (int e = 0; e < 16; e++) acc = fmaf(wr[e], be2[e * 32 + a], acc);
    out[i] = acc;
}

// ---------------- reduce: out[i][a] += sum_bx partial[by][bx][r][a] ----------------
__global__ __launch_bounds__(256)
void reduce_kernel(const float* __restrict__ partial, float* __restrict__ out) {
    int t = blockIdx.x * 256 + threadIdx.x;      // B * 8 threads
    int a4 = t & 7, i = t >> 3;
    int by = i >> 8, r = i & 255;
    const float* p = partial + (size_t)by * 16 * 8192 + r * 32 + a4 * 4;
    f32x4 s = *(const f32x4*)(out + (size_t)i * 32 + a4 * 4);
#pragma unroll
    for (int bx = 0; bx < 16; bx++) s += *(const f32x4*)(p + (size_t)bx * 8192);
    *(f32x4*)(out + (size_t)i * 32 + a4 * 4) = s;
}

// ================= 256x256 GEMM — reg-pipelined phases, 1 barrier/tile =================
// 8 waves (2Mx4N), BK=64, LDS 128KiB double-buffered, swizzle byte ^= (row&7)<<4.
// Reads for phase p+1 are issued BEFORE phase p's MFMAs; no forced lgkmcnt(0) —
// compiler emits counted waits, LDS-read latency hides under the MFMA pipe.
// MODE 0: C = bf16(relu(acc+bias))
// MODE 2: expert fused — eh = relu(acc+be1)*wsel -> LDS -> GEMM2 vs We2t[e]
//         -> f32 partial[by][e][256][32]; expert-locality grid mapping.
// MODE 3: dual output — cols <1024 -> C (bias), cols >=1024 -> C2 (bias2, N2=256)
template<int MODE>
__global__ __launch_bounds__(512, 2)
void gemm256(const short* __restrict__ A, const short* __restrict__ Bt,
             const float* __restrict__ bias, const float* __restrict__ wselp,
             const short* __restrict__ W2, short* __restrict__ C,
             float* __restrict__ pout, const float* __restrict__ bias2,
             short* __restrict__ C2, int M, int N, int K) {
    extern __shared__ __align__(16) short lds[];
    const int tid = threadIdx.x;
    const int w = tid >> 6, lane = tid & 63;
    const int wr = w >> 2, wc = w & 3;

    const int gx = gridDim.x;
    const int b = blockIdx.y * gx + blockIdx.x;
    int bx, by;
    if (MODE == 2) {
        // expert-locality map: all 16 bx of a by adjacent on one XCD
        const int x = b & 7, i = b >> 3;          // 4096 blocks: x=XCD, i seq per XCD
        by = x * 32 + (i >> 4);
        bx = i & 15;
    } else {
        // bijective XCD swizzle (nwg % 8 == 0 for all our launches)
        const int per = (gx * gridDim.y) >> 3;
        const int sb = (b & 7) * per + (b >> 3);
        bx = sb % gx; by = sb / gx;
    }
    const int tm = by * 256, tn = bx * 256;

    const int rih = w * 8 + (lane >> 3);
    const int colel = (((lane & 7) ^ (lane >> 3)) << 3);
    const short* pA = A + (size_t)(tm + rih) * K + colel;
    const short* pB = Bt + (size_t)(tn + rih) * K + colel;
    const size_t rK64 = (size_t)64 * K, rK128 = (size_t)128 * K;
    short* const ldsw = lds + w * 512;

#define STG_A(buf, h, t) do { \
        const short* s_ = pA + (size_t)(h) * rK128 + (size_t)(t) * 64; \
        short* d_ = ldsw + (buf) * 32768 + (h) * 8192; \
        gload16(s_, d_); \
        gload16(s_ + rK64, d_ + 4096); } while (0)
#define STG_B(buf, h, t) do { \
        const short* s_ = pB + (size_t)(h) * rK128 + (size_t)(t) * 64; \
        short* d_ = ldsw + (buf) * 32768 + 16384 + (h) * 8192; \
        gload16(s_, d_); \
        gload16(s_ + rK64, d_ + 4096); } while (0)

    const int rA = lane & 15, q = lane >> 4;
    const int csw0 = ((q << 4)) ^ ((lane & 7) << 4);
    const int csw1 = (64 + (q << 4)) ^ ((lane & 7) << 4);
    const char* const ldsB_ = (const char*)lds;
    const int aBase0 = wr * 16384 + rA * 128;
    const int bBase0 = 32768 + (wc >> 1) * 16384 + ((wc & 1) * 64 + rA) * 128;

    f32x4 acc[8][4] = {};
    short8 aL[4][2], aH[4][2], b0[2][2], b1[2][2];
    const int nt = K >> 6;

    // prologue: stage tile0; then initial aL/b0 reads
    STG_A(0, 0, 0); STG_A(0, 1, 0); STG_B(0, 0, 0); STG_B(0, 1, 0);
    WAITV0(); BAR();
    {
        const char* pa = ldsB_ + aBase0;
        const char* pb = ldsB_ + bBase0;
#pragma unroll
        for (int m = 0; m < 4; m++) {
            aL[m][0] = *(const short8*)(pa + m * 2048 + csw0);
            aL[m][1] = *(const short8*)(pa + m * 2048 + csw1);
        }
#pragma unroll
        for (int n = 0; n < 2; n++) {
            b0[n][0] = *(const short8*)(pb + n * 2048 + csw0);
            b0[n][1] = *(const short8*)(pb + n * 2048 + csw1);
        }
    }

    for (int t = 0; t < nt; ++t) {
        const int cur = t & 1, nxt = cur ^ 1;
        const char* pa = ldsB_ + cur * 65536 + aBase0;
        const char* pb = ldsB_ + cur * 65536 + bBase0;
        // ph1: issue b1 reads + next-tile staging; MFMA (lo,lo) on aL,b0
#pragma unroll
        for (int n = 0; n < 2; n++) {
            b1[n][0] = *(const short8*)(pb + (2 + n) * 2048 + csw0);
            b1[n][1] = *(const short8*)(pb + (2 + n) * 2048 + csw1);
        }
        if (t + 1 < nt) {
            STG_A(nxt, 0, t + 1); STG_A(nxt, 1, t + 1);
            STG_B(nxt, 0, t + 1); STG_B(nxt, 1, t + 1);
        }
        __builtin_amdgcn_s_setprio(1);
#pragma unroll
        for (int m = 0; m < 4; m++)
#pragma unroll
            for (int n = 0; n < 2; n++) {
                acc[m][n] = __builtin_amdgcn_mfma_f32_16x16x32_bf16(aL[m][0], b0[n][0], acc[m][n], 0, 0, 0);
                acc[m][n] = __builtin_amdgcn_mfma_f32_16x16x32_bf16(aL[m][1], b0[n][1], acc[m][n], 0, 0, 0);
            }
        __builtin_amdgcn_s_setprio(0);
        // ph2: issue aH reads; MFMA (lo,hi) on aL,b1
#pragma unroll
        for (int m = 0; m < 4; m++) {
            aH[m][0] = *(const short8*)(pa + (4 + m) * 2048 + csw0);
            aH[m][1] = *(const short8*)(pa + (4 + m) * 2048 + csw1);
        }
        __builtin_amdgcn_s_setprio(1);
#pragma unroll
        for (int m = 0; m < 4; m++)
#pragma unroll
            for (int n = 0; n < 2; n++) {
                acc[m][2 + n] = __builtin_amdgcn_mfma_f32_16x16x32_bf16(aL[m][0], b1[n][0], acc[m][2 + n], 0, 0, 0);
                acc[m][2 + n] = __builtin_amdgcn_mfma_f32_16x16x32_bf16(aL[m][1], b1[n][1], acc[m][2 + n], 0, 0, 0);
            }
        __builtin_amdgcn_s_setprio(0);
        // ph3: MFMA (hi,hi) on aH,b1
        __builtin_amdgcn_s_setprio(1);
#pragma unroll
        for (int m = 0; m < 4; m++)
#pragma unroll
            for (int n = 0; n < 2; n++) {
                acc[4 + m][2 + n] = __builtin_amdgcn_mfma_f32_16x16x32_bf16(aH[m][0], b1[n][0], acc[4 + m][2 + n], 0, 0, 0);
                acc[4 + m][2 + n] = __builtin_amdgcn_mfma_f32_16x16x32_bf16(aH[m][1], b1[n][1], acc[4 + m][2 + n], 0, 0, 0);
            }
        __builtin_amdgcn_s_setprio(0);
        // ph4: MFMA (hi,lo) on aH,b0; boundary
        __builtin_amdgcn_s_setprio(1);
#pragma unroll
        for (int m = 0; m < 4; m++)
#pragma unroll
            for (int n = 0; n < 2; n++) {
                acc[4 + m][n] = __builtin_amdgcn_mfma_f32_16x16x32_bf16(aH[m][0], b0[n][0], acc[4 + m][n], 0, 0, 0);
                acc[4 + m][n] = __builtin_amdgcn_mfma_f32_16x16x32_bf16(aH[m][1], b0[n][1], acc[4 + m][n], 0, 0, 0);
            }
        __builtin_amdgcn_s_setprio(0);
        WAITV0(); BAR();
        // issue next tile's aL/b0 reads (buffer nxt, now resident)
        if (t + 1 < nt) {
            const char* qa = ldsB_ + nxt * 65536 + aBase0;
            const char* qb = ldsB_ + nxt * 65536 + bBase0;
#pragma unroll
            for (int m = 0; m < 4; m++) {
                aL[m][0] = *(const short8*)(qa + m * 2048 + csw0);
                aL[m][1] = *(const short8*)(qa + m * 2048 + csw1);
            }
#pragma unroll
            for (int n = 0; n < 2; n++) {
                b0[n][0] = *(const short8*)(qb + n * 2048 + csw0);
                b0[n][1] = *(const short8*)(qb + n * 2048 + csw1);
            }
        }
    }
#undef STG_A
#undef STG_B

    const int q4 = q * 4;
    float biasv[4];
#pragma unroll
    for (int n = 0; n < 4; n++) {
        const int col = tn + wc * 64 + n * 16 + rA;
        biasv[n] = (MODE == 3 && tn >= 1024) ? bias2[col - 1024] : bias[col];
    }

    if (MODE == 2) {
        // eh -> LDS (bf16, wsel-scaled, XOR-swizzled), whole 128KB
        const int e = tn >> 8;
        char* ldsc = (char*)lds;
#pragma unroll
        for (int m = 0; m < 8; m++)
#pragma unroll
            for (int rr = 0; rr < 4; rr++) {
                const int row = wr * 128 + m * 16 + q4 + rr;
                const float ws = wselp[(size_t)(tm + row) * 16 + e];
#pragma unroll
                for (int n = 0; n < 4; n++) {
                    const int col = wc * 64 + n * 16 + rA;
                    const float v = fmaxf(acc[m][n][rr] + biasv[n], 0.f) * ws;
                    *(short*)(ldsc + row * 512 + ((col * 2) ^ ((row & 7) << 4))) = f2b(v);
                }
            }
        asm volatile("s_waitcnt lgkmcnt(0)" ::: "memory");
        BAR();
        f32x4 g2[2][2] = {};
#pragma unroll
        for (int k2 = 0; k2 < 8; ++k2) {
            short8 a2[2], b2[2];
#pragma unroll
            for (int m2 = 0; m2 < 2; m2++) {
                const int row = w * 32 + m2 * 16 + rA;
                a2[m2] = *(const short8*)(ldsc + row * 512 + ((k2 * 64 + q * 16) ^ ((row & 7) << 4)));
            }
#pragma unroll
            for (int n2 = 0; n2 < 2; n2++)
                b2[n2] = *(const short8*)(W2 + (size_t)(e * 32 + n2 * 16 + rA) * 256 + k2 * 32 + q * 8);
#pragma unroll
            for (int m2 = 0; m2 < 2; m2++)
#pragma unroll
                for (int n2 = 0; n2 < 2; n2++)
                    g2[m2][n2] = __builtin_amdgcn_mfma_f32_16x16x32_bf16(a2[m2], b2[n2], g2[m2][n2], 0, 0, 0);
        }
        float* pp = pout + ((size_t)(tm >> 8) * 16 + e) * 8192;
#pragma unroll
        for (int m2 = 0; m2 < 2; m2++)
#pragma unroll
            for (int rr = 0; rr < 4; rr++) {
                const int row = w * 32 + m2 * 16 + q4 + rr;
#pragma unroll
                for (int n2 = 0; n2 < 2; n2++)
                    pp[row * 32 + n2 * 16 + rA] = g2[m2][n2][rr];
            }
        return;
    }

    // MODE 0 / MODE 3 epilogue
#pragma unroll
    for (int m = 0; m < 8; m++)
#pragma unroll
        for (int rr = 0; rr < 4; rr++) {
            const int row = tm + wr * 128 + m * 16 + q4 + rr;
#pragma unroll
            for (int n = 0; n < 4; n++) {
                const int col = tn + wc * 64 + n * 16 + rA;
                float v = fmaxf(acc[m][n][rr] + biasv[n], 0.f);
                if (MODE == 3 && tn >= 1024)
                    C2[(size_t)row * 256 + (col - 1024)] = f2b(v);
                else
                    C[(size_t)row * N + col] = f2b(v);
            }
        }
}

extern "C" void kernel_launch(void* const* d_in, const int* in_sizes, int n_in,
                              void* d_out, int out_size, void* d_ws, size_t ws_size,
                              hipStream_t stream) {
    const float* obs = (const float*)d_in[0];
    const float* Wb0 = (const float*)d_in[1]; const float* bb0 = (const float*)d_in[2];
    const float* Wb1 = (const float*)d_in[3]; const float* bb1 = (const float*)d_in[4];
    const float* Wb2 = (const float*)d_in[5]; const float* bb2 = (const float*)d_in[6];
    const float* We1 = (const float*)d_in[7]; const float* be1 = (const float*)d_in[8];
    const float* We2 = (const float*)d_in[9]; const float* be2 = (const float*)d_in[10];
    const float* Ws0 = (const float*)d_in[11]; const float* bs0 = (const float*)d_in[12];
    const float* Ws1 = (const float*)d_in[13]; const float* bs1 = (const float*)d_in[14];
    const float* Ws2 = (const float*)d_in[15]; const float* bs2 = (const float*)d_in[16];

    const int B = 65536;
    char* ws = (char*)d_ws;
    size_t off = 0;
    auto alloc = [&](size_t bytes) { void* p = ws + off; off += (bytes + 255) & ~(size_t)255; return p; };
    short* obs_bf = (short*)alloc((size_t)B * 512 * 2);
    short* h1     = (short*)alloc((size_t)B * 1024 * 2);   // dead after Wb1; reused as partial
    short* h2     = (short*)alloc((size_t)B * 1024 * 2);   // dead after Wb2; partial tail
    short* hbuf   = (short*)alloc((size_t)B * 512 * 2);
    short* s0     = (short*)alloc((size_t)B * 256 * 2);
    float* wsel   = (float*)alloc((size_t)B * 16 * 4);
    short* WbS0t  = (short*)alloc((size_t)1280 * 512 * 2); // [Wb0t(1024) ; Ws0t(256)]
    short* Wb1t   = (short*)alloc((size_t)1024 * 1024 * 2);
    short* Wb2t   = (short*)alloc((size_t)1024 * 512 * 2);
    short* We1t   = (short*)alloc((size_t)16 * 512 * 256 * 2);
    short* We2t   = (short*)alloc((size_t)16 * 256 * 32 * 2);
    short* Ws1t   = (short*)alloc((size_t)256 * 128 * 2);
    short* Ws2t   = (short*)alloc((size_t)128 * 16 * 2);
    // partial [256 by][16 e][256 r][32 a] f32 = 134.2 MB, aliases dead h1(+h2 head)
    float* partial = (float*)h1;

    static int inited = 0;
    if (!inited) {
        hipFuncSetAttribute(reinterpret_cast<const void*>(gemm256<0>),
                            hipFuncAttributeMaxDynamicSharedMemorySize, 131072);
        hipFuncSetAttribute(reinterpret_cast<const void*>(gemm256<2>),
                            hipFuncAttributeMaxDynamicSharedMemorySize, 131072);
        hipFuncSetAttribute(reinterpret_cast<const void*>(gemm256<3>),
                            hipFuncAttributeMaxDynamicSharedMemorySize, 131072);
        inited = 1;
    }

    // --- preprocessing: casts / transposes ---
    cast_bf16_kernel<<<(B * 512 / 8 + 255) / 256, 256, 0, stream>>>(obs, obs_bf, B * 512 / 8);
    transpose_cast_kernel<<<dim3((1024 * 512 / 8 + 255) / 256, 1), 256, 0, stream>>>(Wb0, WbS0t, 512, 1024, 1024 * 512 / 8);
    transpose_cast_kernel<<<dim3((256 * 512 / 8 + 255) / 256, 1), 256, 0, stream>>>(Ws0, WbS0t + (size_t)1024 * 512, 512, 256, 256 * 512 / 8);
    transpose_cast_kernel<<<dim3((1024 * 1024 / 8 + 255) / 256, 1), 256, 0, stream>>>(Wb1, Wb1t, 1024, 1024, 1024 * 1024 / 8);
    transpose_cast_kernel<<<dim3((512 * 1024 / 8 + 255) / 256, 1), 256, 0, stream>>>(Wb2, Wb2t, 1024, 512, 512 * 1024 / 8);
    transpose_cast_kernel<<<dim3((256 * 512 / 8 + 255) / 256, 16), 256, 0, stream>>>(We1, We1t, 512, 256, 256 * 512 / 8);
    transpose_cast_kernel<<<dim3((32 * 256 / 8 + 255) / 256, 16), 256, 0, stream>>>(We2, We2t, 256, 32, 32 * 256 / 8);
    transpose_cast_kernel<<<dim3((128 * 256 / 8 + 255) / 256, 1), 256, 0, stream>>>(Ws1, Ws1t, 256, 128, 128 * 256 / 8);
    transpose_cast_kernel<<<dim3((16 * 128 / 8 + 255) / 256, 1), 256, 0, stream>>>(Ws2, Ws2t, 128, 16, 16 * 128 / 8);

    // --- Wb0 + selector-L0 fused (dual output h1 / s0) ---
    gemm256<3><<<dim3(5, B / 256), 512, 131072, stream>>>(
        obs_bf, WbS0t, bb0, nullptr, nullptr, h1, nullptr, bs0, s0, B, 1024, 512);
    // --- selector tail: s0 -> s1 -> softmax -> wsel ; out = sum_e wsel*be2 ---
    sel_fused<<<B / 128, 256, 0, stream>>>(s0, Ws1t, bs1, Ws2t, bs2, wsel);
    out_init_kernel<<<B * 32 / 256, 256, 0, stream>>>(wsel, be2, (float*)d_out);

    // --- backbone ---
    gemm256<0><<<dim3(4, B / 256), 512, 131072, stream>>>(
        h1, Wb1t, bb1, nullptr, nullptr, h2, nullptr, nullptr, nullptr, B, 1024, 1024);
    gemm256<0><<<dim3(2, B / 256), 512, 131072, stream>>>(
        h2, Wb2t, bb2, nullptr, nullptr, hbuf, nullptr, nullptr, nullptr, B, 512, 1024);

    // --- experts: single fused dispatch (GEMM1 + in-block GEMM2 -> partials) ---
    gemm256<2><<<dim3(16, B / 256), 512, 131072, stream>>>(
        hbuf, We1t, be1, wsel, We2t, nullptr, partial, nullptr, nullptr, B, 4096, 512);
    reduce_kernel<<<B * 8 / 256, 256, 0, stream>>>(partial, (float*)d_out);
}

// Round 8
// 980.250 us; speedup vs baseline: 2.0177x; 1.0282x over previous
//
#include <hip/hip_runtime.h>
#include <hip/hip_bf16.h>
#include <stdint.h>

typedef __attribute__((ext_vector_type(8))) short short8;
typedef __attribute__((ext_vector_type(4))) float f32x4;

__device__ __forceinline__ float b2f(short s) {
    union { unsigned u; float f; } v; v.u = ((unsigned)(unsigned short)s) << 16; return v.f;
}
__device__ __forceinline__ short f2b(float f) {
    union { float f; unsigned u; } v; v.f = f;
    unsigned r = (v.u + 0x7FFF + ((v.u >> 16) & 1)) >> 16;
    return (short)r;
}

// async global->LDS, 16B per lane. LDS dest is wave-uniform base + lane*16.
__device__ __forceinline__ void gload16(const void* g, void* l) {
    __builtin_amdgcn_global_load_lds(
        (const __attribute__((address_space(1))) void*)(uintptr_t)g,
        (__attribute__((address_space(3))) void*)(uintptr_t)l,
        16, 0, 0);
}

#define BAR()     asm volatile("s_barrier" ::: "memory")
#define WAITV0()  asm volatile("s_waitcnt vmcnt(0)" ::: "memory")

// ---------------- cast fp32 -> bf16 (8 elems/thread) ----------------
__global__ __launch_bounds__(256) void cast_bf16_kernel(
    const float* __restrict__ src, short* __restrict__ dst, int n8) {
    int i = blockIdx.x * 256 + threadIdx.x;
    if (i >= n8) return;
    const float4* s = (const float4*)src + (size_t)i * 2;
    float4 x0 = s[0], x1 = s[1];
    short8 o;
    o[0] = f2b(x0.x); o[1] = f2b(x0.y); o[2] = f2b(x0.z); o[3] = f2b(x0.w);
    o[4] = f2b(x1.x); o[5] = f2b(x1.y); o[6] = f2b(x1.z); o[7] = f2b(x1.w);
    *((short8*)dst + i) = o;
}

// ---------- transpose-cast W[K,N] f32 -> Wt[N,K] bf16 (8 k per thread) ----------
__global__ __launch_bounds__(256) void transpose_cast_kernel(
    const float* __restrict__ W, short* __restrict__ Wt, int K, int N, int total) {
    int t = blockIdx.x * 256 + threadIdx.x;
    if (t >= total) return;
    const float* src = W + (size_t)blockIdx.y * K * N;
    short* dst = Wt + (size_t)blockIdx.y * K * N;
    int n = t % N;
    int k0 = (t / N) * 8;
    short8 o;
#pragma unroll
    for (int i = 0; i < 8; i++) o[i] = f2b(src[(size_t)(k0 + i) * N + n]);
    *(short8*)(dst + (size_t)n * K + k0) = o;
}

// ---------------- fused selector: s0 -> s1 -> logits -> softmax -> wsel ----------------
__global__ __launch_bounds__(256, 3)
void sel_fused(const short* __restrict__ s0, const short* __restrict__ Ws1t,
               const float* __restrict__ bs1, const short* __restrict__ Ws2t,
               const float* __restrict__ bs2, float* __restrict__ wsel) {
    __shared__ __align__(16) short As[128 * 32];
    __shared__ __align__(16) short Bs[128 * 32];
    __shared__ __align__(16) short s1l[128 * 136];
    const int tid = threadIdx.x;
    const int w = tid >> 6, lane = tid & 63;
    const int tm = blockIdx.x * 128;
    const int wm = (w & 1) * 64, wn = (w >> 1) * 64;
    const int r = lane & 15, q = lane >> 4, qk = q * 8;

    const int c0 = w * 2, c1 = w * 2 + 1;
    const int srow0 = c0 * 16 + (lane >> 2);
    const int srow1 = c1 * 16 + (lane >> 2);
    const int skk = (lane & 3) * 8;
    const short* gA0 = s0 + (size_t)(tm + srow0) * 256 + skk;
    const short* gA1 = s0 + (size_t)(tm + srow1) * 256 + skk;
    const short* gB0 = Ws1t + (size_t)srow0 * 256 + skk;
    const short* gB1 = Ws1t + (size_t)srow1 * 256 + skk;
    short* lA0 = &As[c0 * 512]; short* lA1 = &As[c1 * 512];
    short* lB0 = &Bs[c0 * 512]; short* lB1 = &Bs[c1 * 512];

    f32x4 acc[4][4] = {};
    for (int k0 = 0; k0 < 256; k0 += 32) {
        gload16(gA0 + k0, lA0);
        gload16(gA1 + k0, lA1);
        gload16(gB0 + k0, lB0);
        gload16(gB1 + k0, lB1);
        __syncthreads();
        short8 a[4], b[4];
#pragma unroll
        for (int i = 0; i < 4; i++) a[i] = *(const short8*)&As[(wm + i * 16 + r) * 32 + qk];
#pragma unroll
        for (int j = 0; j < 4; j++) b[j] = *(const short8*)&Bs[(wn + j * 16 + r) * 32 + qk];
#pragma unroll
        for (int i = 0; i < 4; i++)
#pragma unroll
            for (int j = 0; j < 4; j++)
                acc[i][j] = __builtin_amdgcn_mfma_f32_16x16x32_bf16(a[i], b[j], acc[i][j], 0, 0, 0);
        __syncthreads();
    }
#pragma unroll
    for (int j = 0; j < 4; j++) {
        int col = wn + j * 16 + r;
        float bj = bs1[col];
#pragma unroll
        for (int i = 0; i < 4; i++)
#pragma unroll
            for (int rr = 0; rr < 4; rr++) {
                int row = wm + i * 16 + q * 4 + rr;
                s1l[row * 136 + col] = f2b(fmaxf(acc[i][j][rr] + bj, 0.f));
            }
    }
    __syncthreads();
    f32x4 acc3[2] = {};
#pragma unroll
    for (int k3 = 0; k3 < 4; ++k3) {
        short8 b3 = *(const short8*)(Ws2t + (size_t)r * 128 + k3 * 32 + qk);
#pragma unroll
        for (int m2 = 0; m2 < 2; m2++) {
            short8 a3 = *(const short8*)&s1l[(w * 32 + m2 * 16 + r) * 136 + k3 * 32 + qk];
            acc3[m2] = __builtin_amdgcn_mfma_f32_16x16x32_bf16(a3, b3, acc3[m2], 0, 0, 0);
        }
    }
    float bse = bs2[r];
#pragma unroll
    for (int m2 = 0; m2 < 2; m2++)
#pragma unroll
        for (int rr = 0; rr < 4; rr++) {
            int row = tm + w * 32 + m2 * 16 + q * 4 + rr;
            float v = acc3[m2][rr] + bse;
            float m = v;
#pragma unroll
            for (int off = 8; off >= 1; off >>= 1) m = fmaxf(m, __shfl_xor(m, off, 16));
            float ex = __expf(v - m);
            float s = ex;
#pragma unroll
            for (int off = 8; off >= 1; off >>= 1) s += __shfl_xor(s, off, 16);
            wsel[(size_t)row * 16 + r] = ex / s;
        }
}

// ------- reduce: out[i][a] = sum_e wsel[i,e]*be2[e,a] + sum_bx partial[by][bx][r][a] -------
__global__ __launch_bounds__(256)
void reduce_kernel(const float* __restrict__ partial, const float* __restrict__ wsel,
                   const float* __restrict__ be2, float* __restrict__ out) {
    int t = blockIdx.x * 256 + threadIdx.x;      // B * 8 threads
    int a4 = t & 7, i = t >> 3;
    int by = i >> 8, r = i & 255;
    const float* p = partial + (size_t)by * 16 * 8192 + r * 32 + a4 * 4;
    const float* wr = wsel + (size_t)i * 16;
    f32x4 s = {};
#pragma unroll
    for (int e = 0; e < 16; e++) {
        float wv = wr[e];
        const float* b2 = be2 + e * 32 + a4 * 4;
#pragma unroll
        for (int j = 0; j < 4; j++) s[j] = fmaf(wv, b2[j], s[j]);
    }
#pragma unroll
    for (int bx = 0; bx < 16; bx++) s += *(const f32x4*)(p + (size_t)bx * 8192);
    *(f32x4*)(out + (size_t)i * 32 + a4 * 4) = s;
}

// ================= 256x256 GEMM — reg-pipelined phases, 1 barrier/tile =================
// 8 waves (2Mx4N), BK=64, LDS 128KiB double-buffered, swizzle byte ^= (row&7)<<4.
// Reads for phase p+1 are issued BEFORE phase p's MFMAs; no forced lgkmcnt(0) —
// compiler emits counted waits, LDS-read latency hides under the MFMA pipe.
// Boundary uses ONLY vmcnt(0) (spill-proof) + barrier.   [VERIFIED: round 6]
// MODE 0: C = bf16(relu(acc+bias))
// MODE 2: expert fused — eh = relu(acc+be1)*wsel -> LDS -> GEMM2 vs We2t[e]
//         -> f32 partial[by][e][256][32]
// MODE 3: dual output — cols <1024 -> C (bias), cols >=1024 -> C2 (bias2, N2=256)
template<int MODE>
__global__ __launch_bounds__(512, 2)
void gemm256(const short* __restrict__ A, const short* __restrict__ Bt,
             const float* __restrict__ bias, const float* __restrict__ wselp,
             const short* __restrict__ W2, short* __restrict__ C,
             float* __restrict__ pout, const float* __restrict__ bias2,
             short* __restrict__ C2, int M, int N, int K) {
    extern __shared__ __align__(16) short lds[];
    const int tid = threadIdx.x;
    const int w = tid >> 6, lane = tid & 63;
    const int wr = w >> 2, wc = w & 3;

    const int gx = gridDim.x;
    const int b = blockIdx.y * gx + blockIdx.x;
    int bx, by;
    {
        // bijective XCD swizzle (nwg % 8 == 0 for all our launches)
        const int per = (gx * gridDim.y) >> 3;
        const int sb = (b & 7) * per + (b >> 3);
        bx = sb % gx; by = sb / gx;
    }
    const int tm = by * 256, tn = bx * 256;

    const int rih = w * 8 + (lane >> 3);
    const int colel = (((lane & 7) ^ (lane >> 3)) << 3);
    const short* pA = A + (size_t)(tm + rih) * K + colel;
    const short* pB = Bt + (size_t)(tn + rih) * K + colel;
    const size_t rK64 = (size_t)64 * K, rK128 = (size_t)128 * K;
    short* const ldsw = lds + w * 512;

#define STG_A(buf, h, t) do { \
        const short* s_ = pA + (size_t)(h) * rK128 + (size_t)(t) * 64; \
        short* d_ = ldsw + (buf) * 32768 + (h) * 8192; \
        gload16(s_, d_); \
        gload16(s_ + rK64, d_ + 4096); } while (0)
#define STG_B(buf, h, t) do { \
        const short* s_ = pB + (size_t)(h) * rK128 + (size_t)(t) * 64; \
        short* d_ = ldsw + (buf) * 32768 + 16384 + (h) * 8192; \
        gload16(s_, d_); \
        gload16(s_ + rK64, d_ + 4096); } while (0)

    const int rA = lane & 15, q = lane >> 4;
    const int csw0 = ((q << 4)) ^ ((lane & 7) << 4);
    const int csw1 = (64 + (q << 4)) ^ ((lane & 7) << 4);
    const char* const ldsB_ = (const char*)lds;
    const int aBase0 = wr * 16384 + rA * 128;
    const int bBase0 = 32768 + (wc >> 1) * 16384 + ((wc & 1) * 64 + rA) * 128;

    f32x4 acc[8][4] = {};
    short8 aL[4][2], aH[4][2], b0[2][2], b1[2][2];
    const int nt = K >> 6;

    // prologue: stage tile0; then initial aL/b0 reads
    STG_A(0, 0, 0); STG_A(0, 1, 0); STG_B(0, 0, 0); STG_B(0, 1, 0);
    WAITV0(); BAR();
    {
        const char* pa = ldsB_ + aBase0;
        const char* pb = ldsB_ + bBase0;
#pragma unroll
        for (int m = 0; m < 4; m++) {
            aL[m][0] = *(const short8*)(pa + m * 2048 + csw0);
            aL[m][1] = *(const short8*)(pa + m * 2048 + csw1);
        }
#pragma unroll
        for (int n = 0; n < 2; n++) {
            b0[n][0] = *(const short8*)(pb + n * 2048 + csw0);
            b0[n][1] = *(const short8*)(pb + n * 2048 + csw1);
        }
    }

    for (int t = 0; t < nt; ++t) {
        const int cur = t & 1, nxt = cur ^ 1;
        const char* pa = ldsB_ + cur * 65536 + aBase0;
        const char* pb = ldsB_ + cur * 65536 + bBase0;
        // ph1: issue b1 reads + next-tile staging; MFMA (lo,lo) on aL,b0
#pragma unroll
        for (int n = 0; n < 2; n++) {
            b1[n][0] = *(const short8*)(pb + (2 + n) * 2048 + csw0);
            b1[n][1] = *(const short8*)(pb + (2 + n) * 2048 + csw1);
        }
        if (t + 1 < nt) {
            STG_A(nxt, 0, t + 1); STG_A(nxt, 1, t + 1);
            STG_B(nxt, 0, t + 1); STG_B(nxt, 1, t + 1);
        }
        __builtin_amdgcn_s_setprio(1);
#pragma unroll
        for (int m = 0; m < 4; m++)
#pragma unroll
            for (int n = 0; n < 2; n++) {
                acc[m][n] = __builtin_amdgcn_mfma_f32_16x16x32_bf16(aL[m][0], b0[n][0], acc[m][n], 0, 0, 0);
                acc[m][n] = __builtin_amdgcn_mfma_f32_16x16x32_bf16(aL[m][1], b0[n][1], acc[m][n], 0, 0, 0);
            }
        __builtin_amdgcn_s_setprio(0);
        // ph2: issue aH reads; MFMA (lo,hi) on aL,b1
#pragma unroll
        for (int m = 0; m < 4; m++) {
            aH[m][0] = *(const short8*)(pa + (4 + m) * 2048 + csw0);
            aH[m][1] = *(const short8*)(pa + (4 + m) * 2048 + csw1);
        }
        __builtin_amdgcn_s_setprio(1);
#pragma unroll
        for (int m = 0; m < 4; m++)
#pragma unroll
            for (int n = 0; n < 2; n++) {
                acc[m][2 + n] = __builtin_amdgcn_mfma_f32_16x16x32_bf16(aL[m][0], b1[n][0], acc[m][2 + n], 0, 0, 0);
                acc[m][2 + n] = __builtin_amdgcn_mfma_f32_16x16x32_bf16(aL[m][1], b1[n][1], acc[m][2 + n], 0, 0, 0);
            }
        __builtin_amdgcn_s_setprio(0);
        // ph3: MFMA (hi,hi) on aH,b1
        __builtin_amdgcn_s_setprio(1);
#pragma unroll
        for (int m = 0; m < 4; m++)
#pragma unroll
            for (int n = 0; n < 2; n++) {
                acc[4 + m][2 + n] = __builtin_amdgcn_mfma_f32_16x16x32_bf16(aH[m][0], b1[n][0], acc[4 + m][2 + n], 0, 0, 0);
                acc[4 + m][2 + n] = __builtin_amdgcn_mfma_f32_16x16x32_bf16(aH[m][1], b1[n][1], acc[4 + m][2 + n], 0, 0, 0);
            }
        __builtin_amdgcn_s_setprio(0);
        // ph4: MFMA (hi,lo) on aH,b0; boundary
        __builtin_amdgcn_s_setprio(1);
#pragma unroll
        for (int m = 0; m < 4; m++)
#pragma unroll
            for (int n = 0; n < 2; n++) {
                acc[4 + m][n] = __builtin_amdgcn_mfma_f32_16x16x32_bf16(aH[m][0], b0[n][0], acc[4 + m][n], 0, 0, 0);
                acc[4 + m][n] = __builtin_amdgcn_mfma_f32_16x16x32_bf16(aH[m][1], b0[n][1], acc[4 + m][n], 0, 0, 0);
            }
        __builtin_amdgcn_s_setprio(0);
        WAITV0(); BAR();
        // issue next tile's aL/b0 reads (buffer nxt, now resident)
        if (t + 1 < nt) {
            const char* qa = ldsB_ + nxt * 65536 + aBase0;
            const char* qb = ldsB_ + nxt * 65536 + bBase0;
#pragma unroll
            for (int m = 0; m < 4; m++) {
                aL[m][0] = *(const short8*)(qa + m * 2048 + csw0);
                aL[m][1] = *(const short8*)(qa + m * 2048 + csw1);
            }
#pragma unroll
            for (int n = 0; n < 2; n++) {
                b0[n][0] = *(const short8*)(qb + n * 2048 + csw0);
                b0[n][1] = *(const short8*)(qb + n * 2048 + csw1);
            }
        }
    }
#undef STG_A
#undef STG_B

    const int q4 = q * 4;
    float biasv[4];
#pragma unroll
    for (int n = 0; n < 4; n++) {
        const int col = tn + wc * 64 + n * 16 + rA;
        biasv[n] = (MODE == 3 && tn >= 1024) ? bias2[col - 1024] : bias[col];
    }

    if (MODE == 2) {
        // eh -> LDS (bf16, wsel-scaled, XOR-swizzled), whole 128KB
        const int e = tn >> 8;
        char* ldsc = (char*)lds;
#pragma unroll
        for (int m = 0; m < 8; m++)
#pragma unroll
            for (int rr = 0; rr < 4; rr++) {
                const int row = wr * 128 + m * 16 + q4 + rr;
                const float ws = wselp[(size_t)(tm + row) * 16 + e];
#pragma unroll
                for (int n = 0; n < 4; n++) {
                    const int col = wc * 64 + n * 16 + rA;
                    const float v = fmaxf(acc[m][n][rr] + biasv[n], 0.f) * ws;
                    *(short*)(ldsc + row * 512 + ((col * 2) ^ ((row & 7) << 4))) = f2b(v);
                }
            }
        asm volatile("s_waitcnt lgkmcnt(0)" ::: "memory");
        BAR();
        f32x4 g2[2][2] = {};
#pragma unroll
        for (int k2 = 0; k2 < 8; ++k2) {
            short8 a2[2], b2[2];
#pragma unroll
            for (int m2 = 0; m2 < 2; m2++) {
                const int row = w * 32 + m2 * 16 + rA;
                a2[m2] = *(const short8*)(ldsc + row * 512 + ((k2 * 64 + q * 16) ^ ((row & 7) << 4)));
            }
#pragma unroll
            for (int n2 = 0; n2 < 2; n2++)
                b2[n2] = *(const short8*)(W2 + (size_t)(e * 32 + n2 * 16 + rA) * 256 + k2 * 32 + q * 8);
#pragma unroll
            for (int m2 = 0; m2 < 2; m2++)
#pragma unroll
                for (int n2 = 0; n2 < 2; n2++)
                    g2[m2][n2] = __builtin_amdgcn_mfma_f32_16x16x32_bf16(a2[m2], b2[n2], g2[m2][n2], 0, 0, 0);
        }
        float* pp = pout + ((size_t)(tm >> 8) * 16 + e) * 8192;
#pragma unroll
        for (int m2 = 0; m2 < 2; m2++)
#pragma unroll
            for (int rr = 0; rr < 4; rr++) {
                const int row = w * 32 + m2 * 16 + q4 + rr;
#pragma unroll
                for (int n2 = 0; n2 < 2; n2++)
                    pp[row * 32 + n2 * 16 + rA] = g2[m2][n2][rr];
            }
        return;
    }

    // MODE 0 / MODE 3 epilogue
#pragma unroll
    for (int m = 0; m < 8; m++)
#pragma unroll
        for (int rr = 0; rr < 4; rr++) {
            const int row = tm + wr * 128 + m * 16 + q4 + rr;
#pragma unroll
            for (int n = 0; n < 4; n++) {
                const int col = tn + wc * 64 + n * 16 + rA;
                float v = fmaxf(acc[m][n][rr] + biasv[n], 0.f);
                if (MODE == 3 && tn >= 1024)
                    C2[(size_t)row * 256 + (col - 1024)] = f2b(v);
                else
                    C[(size_t)row * N + col] = f2b(v);
            }
        }
}

extern "C" void kernel_launch(void* const* d_in, const int* in_sizes, int n_in,
                              void* d_out, int out_size, void* d_ws, size_t ws_size,
                              hipStream_t stream) {
    const float* obs = (const float*)d_in[0];
    const float* Wb0 = (const float*)d_in[1]; const float* bb0 = (const float*)d_in[2];
    const float* Wb1 = (const float*)d_in[3]; const float* bb1 = (const float*)d_in[4];
    const float* Wb2 = (const float*)d_in[5]; const float* bb2 = (const float*)d_in[6];
    const float* We1 = (const float*)d_in[7]; const float* be1 = (const float*)d_in[8];
    const float* We2 = (const float*)d_in[9]; const float* be2 = (const float*)d_in[10];
    const float* Ws0 = (const float*)d_in[11]; const float* bs0 = (const float*)d_in[12];
    const float* Ws1 = (const float*)d_in[13]; const float* bs1 = (const float*)d_in[14];
    const float* Ws2 = (const float*)d_in[15]; const float* bs2 = (const float*)d_in[16];

    const int B = 65536;
    char* ws = (char*)d_ws;
    size_t off = 0;
    auto alloc = [&](size_t bytes) { void* p = ws + off; off += (bytes + 255) & ~(size_t)255; return p; };
    short* obs_bf = (short*)alloc((size_t)B * 512 * 2);
    short* h1     = (short*)alloc((size_t)B * 1024 * 2);   // dead after Wb1; reused as partial
    short* h2     = (short*)alloc((size_t)B * 1024 * 2);   // dead after Wb2; partial tail
    short* hbuf   = (short*)alloc((size_t)B * 512 * 2);
    short* s0     = (short*)alloc((size_t)B * 256 * 2);
    float* wsel   = (float*)alloc((size_t)B * 16 * 4);
    short* WbS0t  = (short*)alloc((size_t)1280 * 512 * 2); // [Wb0t(1024) ; Ws0t(256)]
    short* Wb1t   = (short*)alloc((size_t)1024 * 1024 * 2);
    short* Wb2t   = (short*)alloc((size_t)1024 * 512 * 2);
    short* We1t   = (short*)alloc((size_t)16 * 512 * 256 * 2);
    short* We2t   = (short*)alloc((size_t)16 * 256 * 32 * 2);
    short* Ws1t   = (short*)alloc((size_t)256 * 128 * 2);
    short* Ws2t   = (short*)alloc((size_t)128 * 16 * 2);
    float* partial = (float*)h1;   // [256][16][256][32] f32 = 134 MB

    static int inited = 0;
    if (!inited) {
        hipFuncSetAttribute(reinterpret_cast<const void*>(gemm256<0>),
                            hipFuncAttributeMaxDynamicSharedMemorySize, 131072);
        hipFuncSetAttribute(reinterpret_cast<const void*>(gemm256<2>),
                            hipFuncAttributeMaxDynamicSharedMemorySize, 131072);
        hipFuncSetAttribute(reinterpret_cast<const void*>(gemm256<3>),
                            hipFuncAttributeMaxDynamicSharedMemorySize, 131072);
        inited = 1;
    }

    // --- preprocessing: casts / transposes ---
    cast_bf16_kernel<<<(B * 512 / 8 + 255) / 256, 256, 0, stream>>>(obs, obs_bf, B * 512 / 8);
    transpose_cast_kernel<<<dim3((1024 * 512 / 8 + 255) / 256, 1), 256, 0, stream>>>(Wb0, WbS0t, 512, 1024, 1024 * 512 / 8);
    transpose_cast_kernel<<<dim3((256 * 512 / 8 + 255) / 256, 1), 256, 0, stream>>>(Ws0, WbS0t + (size_t)1024 * 512, 512, 256, 256 * 512 / 8);
    transpose_cast_kernel<<<dim3((1024 * 1024 / 8 + 255) / 256, 1), 256, 0, stream>>>(Wb1, Wb1t, 1024, 1024, 1024 * 1024 / 8);
    transpose_cast_kernel<<<dim3((512 * 1024 / 8 + 255) / 256, 1), 256, 0, stream>>>(Wb2, Wb2t, 1024, 512, 512 * 1024 / 8);
    transpose_cast_kernel<<<dim3((256 * 512 / 8 + 255) / 256, 16), 256, 0, stream>>>(We1, We1t, 512, 256, 256 * 512 / 8);
    transpose_cast_kernel<<<dim3((32 * 256 / 8 + 255) / 256, 16), 256, 0, stream>>>(We2, We2t, 256, 32, 32 * 256 / 8);
    transpose_cast_kernel<<<dim3((128 * 256 / 8 + 255) / 256, 1), 256, 0, stream>>>(Ws1, Ws1t, 256, 128, 128 * 256 / 8);
    transpose_cast_kernel<<<dim3((16 * 128 / 8 + 255) / 256, 1), 256, 0, stream>>>(Ws2, Ws2t, 128, 16, 16 * 128 / 8);

    // --- Wb0 + selector-L0 fused (dual output h1 / s0) ---
    gemm256<3><<<dim3(5, B / 256), 512, 131072, stream>>>(
        obs_bf, WbS0t, bb0, nullptr, nullptr, h1, nullptr, bs0, s0, B, 1024, 512);
    // --- selector tail ---
    sel_fused<<<B / 128, 256, 0, stream>>>(s0, Ws1t, bs1, Ws2t, bs2, wsel);

    // --- backbone ---
    gemm256<0><<<dim3(4, B / 256), 512, 131072, stream>>>(
        h1, Wb1t, bb1, nullptr, nullptr, h2, nullptr, nullptr, nullptr, B, 1024, 1024);
    gemm256<0><<<dim3(2, B / 256), 512, 131072, stream>>>(
        h2, Wb2t, bb2, nullptr, nullptr, hbuf, nullptr, nullptr, nullptr, B, 512, 1024);

    // --- experts: single fused dispatch (GEMM1 + in-block GEMM2 -> partials) ---
    gemm256<2><<<dim3(16, B / 256), 512, 131072, stream>>>(
        hbuf, We1t, be1, wsel, We2t, nullptr, partial, nullptr, nullptr, B, 4096, 512);
    // --- final reduce (includes sum_e wsel*be2 init term) ---
    reduce_kernel<<<B * 8 / 256, 256, 0, stream>>>(partial, wsel, be2, (float*)d_out);
}